// Round 6
// baseline (7559.844 us; speedup 1.0000x reference)
//
#include <hip/hip_runtime.h>
#include <hip/hip_fp16.h>
#include <math.h>

#define N 1024
#define W1 64
#define W2S 96
#define Q 32
#define NB 32
#define NTHR 1024
#define CHEB_M 16
#define ROUNDS 4
#define NITER 6
#define NEWT 20
#define JSWEEPS 6
#define CCIT 12

#define WFENCE() asm volatile("" ::: "memory")

// ---------------- device state ----------------
__device__ unsigned g_flags[NB*32];
__device__ unsigned g_gen;
__device__ unsigned short g_idx1[N*W1];
__device__ float g_a0[N*W1], g_u[N*W1], g_unew[N*W1], g_s[N*W1], g_snew[N*W1];
__device__ int g_nnz1[N], g_nnz2[N], g_nz8[N];
__device__ unsigned g_rowpT[W2S*N];            // COLUMN-major packed: (idx<<16)|f16(w)
__device__ unsigned short g_jidx[N*W2S];       // row-major idx list
__device__ float g_w2[N*W2S], g_w2fin[N*W2S];
__device__ float g_deg[N], g_sn[N];
__device__ float g_Sd[N*N];
__device__ float g_X0[Q*N], g_X1[Q*N], g_W[Q*N];
__device__ double g_G[Q*Q], g_H[Q*Q];
__device__ float g_F[N*8], g_Fc[N*8];

__device__ __forceinline__ unsigned packrw(unsigned j, float w) {
  __half h = __float2half_rn(w);
  unsigned short bits; __builtin_memcpy(&bits, &h, 2);
  return (j << 16) | (unsigned)bits;
}
__device__ __forceinline__ float unpackw(unsigned v) {
  unsigned short bits = (unsigned short)(v & 0xFFFFu);
  __half h; __builtin_memcpy(&h, &bits, 2);
  return __half2float(h);
}

#define P1(pv) { unsigned _p = (pv); acc += __half2float(__ushort_as_half((unsigned short)(_p & 0xFFFFu))) * xc[_p >> 16]; }

__global__ __launch_bounds__(NTHR) void mega(const float* __restrict__ A, float* __restrict__ out) {
  const int c = blockIdx.x;
  const int t = threadIdx.x;
  const int wv = t >> 6, ln = t & 63;

  __shared__ float xv[3][N];
  __shared__ float wl[N];
  __shared__ float degl[N];
  __shared__ double sM1[Q][Q+1];
  __shared__ double sM2[Q][Q+1];
  __shared__ double sM3[Q][Q+1];
  __shared__ float sFQ[Q][8];
  __shared__ double sTheta[Q];
  __shared__ int   sPerm[Q];
  __shared__ float sCoef[CHEB_M*3];
  __shared__ float sRed[16];
  __shared__ int   sRedI[16];
  __shared__ double sCs[16][2];
  __shared__ int   sPr[16], sQr[16];
  __shared__ int   sLab[N], sLab2[N];
  __shared__ float sB_, sA_, sLamV;
  __shared__ int   sDoneV, sF0, sF1, sKmax;

  float* xb = &xv[0][0];
  unsigned bcnt = 0;

  auto GBAR = [&]() {
    __syncthreads();
    ++bcnt;
    if (t == 0) __builtin_amdgcn_fence(__ATOMIC_RELEASE, "agent");
    if (c == 0) {
      if (t < 64) {
        for (;;) {
          unsigned v = bcnt;
          if (ln < NB - 1)
            v = __hip_atomic_load(&g_flags[(ln + 1) * 32], __ATOMIC_RELAXED, __HIP_MEMORY_SCOPE_AGENT);
          if (__all(v >= bcnt)) break;
          __builtin_amdgcn_s_sleep(1);
        }
        if (ln == 0)
          __hip_atomic_store(&g_gen, bcnt, __ATOMIC_RELAXED, __HIP_MEMORY_SCOPE_AGENT);
      }
    } else if (t == 0) {
      __hip_atomic_store(&g_flags[c * 32], bcnt, __ATOMIC_RELAXED, __HIP_MEMORY_SCOPE_AGENT);
      while (__hip_atomic_load(&g_gen, __ATOMIC_RELAXED, __HIP_MEMORY_SCOPE_AGENT) < bcnt)
        __builtin_amdgcn_s_sleep(1);
    }
    if (t == 0) __builtin_amdgcn_fence(__ATOMIC_ACQUIRE, "agent");
    __syncthreads();
  };

  // coalesced column-major ELL row-dot: thread t owns row t
  auto SPROW = [&](const float* __restrict__ xc) -> float {
    float acc = 0.f;
    const int kmax = sKmax;
    const unsigned* __restrict__ rp = g_rowpT + t;
    for (int k = 0; k < kmax; k += 8) {
      const unsigned* __restrict__ p = rp + k*N;
      unsigned a0 = p[0*N], a1 = p[1*N], a2 = p[2*N], a3 = p[3*N];
      unsigned a4 = p[4*N], a5 = p[5*N], a6 = p[6*N], a7 = p[7*N];
      P1(a0) P1(a1) P1(a2) P1(a3) P1(a4) P1(a5) P1(a6) P1(a7)
    }
    return acc;
  };

  auto CHSTEP = [&](int cu, int pv_, int nx, float al, float be, float ga) {
    const float* xc = xb + cu*N;
    float acc = SPROW(xc);
    float xr = xc[t];
    float o = al*(degl[t]*xr - acc) + be*xr;
    if (ga != 0.f) o += ga * xb[pv_*N + t];
    xb[nx*N + t] = o;
    __syncthreads();
  };

  auto LMUL = [&](int cu) {
    const float* xc = xb + cu*N;
    float acc = SPROW(xc);
    wl[t] = degl[t]*xc[t] - acc;
    __syncthreads();
  };

  auto DEFL = [&](int bu) {
    if (c == 0) {
      xb[bu*N + t] = 0.03125f;
    } else {
      float s = xb[bu*N + t];
      for (int o = 32; o; o >>= 1) s += __shfl_xor(s, o);
      if (ln == 0) sRed[wv] = s;
      __syncthreads();
      float tot = 0.f;
      #pragma unroll
      for (int w = 0; w < 16; w++) tot += sRed[w];
      xb[bu*N + t] -= tot / (float)N;
    }
    __syncthreads();
  };

  auto GHROWS = [&](const float* Xp, int cu) {
    const float* xc = xb + cu*N;
    for (int k = wv; k < Q; k += 16) {
      const float* mx = Xp + k*N;
      const float* mw = g_W + k*N;
      double pg = 0.0, ph = 0.0;
      for (int s = 0; s < 16; s++) {
        int i = ln + s*64;
        double xv_ = (double)xc[i];
        pg += xv_ * (double)mx[i];
        ph += xv_ * (double)mw[i];
      }
      for (int o = 32; o; o >>= 1) { pg += __shfl_xor(pg, o); ph += __shfl_xor(ph, o); }
      if (ln == 0) { g_G[c*Q + k] = pg; g_H[c*Q + k] = ph; }
    }
  };

  // wave-0-local Cholesky + R^-1 (lockstep; WFENCE = compiler ordering only)
  auto CHOLINV = [&]() {
    for (int id = t; id < Q*Q; id += NTHR) sM1[id>>5][id&31] = g_G[id];
    __syncthreads();
    if (wv == 0) {
      const int j = ln & 31;
      const bool lo = ln < 32;
      double fl;
      { double md = 0.0;
        for (int i = 0; i < Q; i++) md = fmax(md, sM1[i][i]);
        fl = md*1e-13 + 1e-280; }
      for (int k = 0; k < Q; k++) {
        double dkk = sM1[k][k]; if (!(dkk > fl)) dkk = fl;
        double rkk = sqrt(dkk);
        if (lo && j > k) sM1[k][j] /= rkk;
        if (ln == 0) sM1[k][k] = rkk;
        WFENCE();
        if (lo) {
          for (int i = k+1; i < Q; i++)
            if (j >= i) sM1[i][j] -= sM1[k][i]*sM1[k][j];
        }
        WFENCE();
      }
      if (lo) {
        for (int i = 0; i < Q; i++) sM2[i][j] = 0.0;
        sM2[j][j] = 1.0/sM1[j][j];
        for (int i = j-1; i >= 0; i--) {
          double sa = 0.0;
          for (int k2 = i+1; k2 <= j; k2++) sa += sM1[i][k2]*sM2[k2][j];
          sM2[i][j] = -sa/sM1[i][i];
        }
      }
    }
    __syncthreads();
  };

  auto RRTRANS = [&]() {   // sM3 = R^-T * sM3 * R^-1
    int i = t >> 5, j = t & 31;
    double a = 0.0;
    for (int k = 0; k <= i; k++) a += sM2[k][i]*sM3[k][j];
    __syncthreads();
    sM1[i][j] = a;
    __syncthreads();
    double b = 0.0;
    for (int k = 0; k <= j; k++) b += sM1[i][k]*sM2[k][j];
    __syncthreads();
    sM3[i][j] = b;
    __syncthreads();
  };

  auto MULR = [&](const float* Xp, int tb) {
    float acc = 0.f;
    #pragma unroll
    for (int k = 0; k < Q; k++) acc += Xp[k*N + t] * (float)sM2[k][c];
    xb[tb*N + t] = acc;
    __syncthreads();
  };

  auto POWA = [&]() {
    if (wv == 0) {
      int rl = ln & 31;
      double v = 1.0, w_ = 0.0, nrm = 1.0;
      for (int it = 0; it < 20; it++) {
        w_ = 0.0;
        for (int k2 = 0; k2 < Q; k2++) w_ += sM3[rl][k2]*__shfl(v, k2);
        nrm = 0.0;
        for (int k2 = 0; k2 < Q; k2++) { double wk = __shfl(w_, k2); nrm += wk*wk; }
        nrm = sqrt(nrm) + 1e-300;
        v = w_/nrm;
      }
      if (ln == 0) {
        float b = sB_;
        float a = (float)(nrm*1.1);
        if (a > 0.9f*b) a = 0.9f*b;
        if (a < 0.02f*b) a = 0.02f*b;
        sA_ = a;
      }
    }
    __syncthreads();
  };

  // wave-0-local Jacobi on sM3 (vectors accumulate in sM1)
  auto JACOBI = [&]() {
    for (int id = t; id < Q*Q; id += NTHR) sM1[id>>5][id&31] = ((id>>5) == (id&31)) ? 1.0 : 0.0;
    __syncthreads();
    if (wv == 0) {
      const int cj = ln & 31, half = ln >> 5;
      for (int sw = 0; sw < JSWEEPS; sw++) {
        for (int rr2 = 0; rr2 < 31; rr2++) {
          if (ln < 16) {
            int p, q;
            if (ln == 0) { p = 31; q = rr2 % 31; }
            else { p = (rr2 + ln) % 31; q = (rr2 + 31 - ln) % 31; }
            sPr[ln] = p; sQr[ln] = q;
            double app = sM3[p][p], aqq = sM3[q][q], apq = sM3[p][q];
            double cth, sth;
            if (fabs(apq) < 1e-280) { cth = 1.0; sth = 0.0; }
            else {
              double ta = (aqq - app)/(2.0*apq);
              double tt = (ta >= 0.0 ? 1.0 : -1.0)/(fabs(ta) + sqrt(1.0 + ta*ta));
              cth = 1.0/sqrt(1.0 + tt*tt); sth = tt*cth;
            }
            sCs[ln][0] = cth; sCs[ln][1] = sth;
          }
          WFENCE();
          #pragma unroll
          for (int s = 0; s < 8; s++) {
            int pi = 2*s + half;
            int p = sPr[pi], q = sQr[pi];
            double cth = sCs[pi][0], sth = sCs[pi][1];
            double hp = sM3[p][cj], hq = sM3[q][cj];
            sM3[p][cj] = cth*hp - sth*hq;
            sM3[q][cj] = sth*hp + cth*hq;
          }
          WFENCE();
          #pragma unroll
          for (int s = 0; s < 8; s++) {
            int pi = 2*s + half;
            int p = sPr[pi], q = sQr[pi];
            double cth = sCs[pi][0], sth = sCs[pi][1];
            double hp = sM3[cj][p], hq = sM3[cj][q];
            sM3[cj][p] = cth*hp - sth*hq;
            sM3[cj][q] = sth*hp + cth*hq;
            double vp = sM1[cj][p], vq = sM1[cj][q];
            sM1[cj][p] = cth*vp - sth*vq;
            sM1[cj][q] = sth*vp + cth*vq;
          }
          WFENCE();
        }
      }
      if (ln < Q) sTheta[ln] = sM3[ln][ln];
    }
    __syncthreads();
  };

  auto SORTP = [&]() {
    if (t == 0) {
      double th[Q]; int pm[Q];
      for (int i = 0; i < Q; i++) { th[i] = sTheta[i]; pm[i] = i; }
      for (int i = 1; i < Q; i++) {
        double x = th[i]; int px = pm[i]; int j = i - 1;
        while (j >= 0 && th[j] > x) { th[j+1] = th[j]; pm[j+1] = pm[j]; j--; }
        th[j+1] = x; pm[j+1] = px;
      }
      for (int i = 0; i < Q; i++) { sTheta[i] = th[i]; sPerm[i] = pm[i]; }
    }
    __syncthreads();
  };

  auto EIG = [&]() {
    degl[t] = g_deg[t];
    __syncthreads();
    float mx = degl[t];
    for (int o = 32; o; o >>= 1) mx = fmaxf(mx, __shfl_xor(mx, o));
    if (ln == 0) sRed[wv] = mx;
    __syncthreads();
    if (t == 0) {
      float mm = 0.f;
      for (int w = 0; w < 16; w++) mm = fmaxf(mm, sRed[w]);
      float b = fmaxf(2.02f*mm, 1e-3f) + 1e-6f;
      sB_ = b; sA_ = 0.5f*b;
    }
    __syncthreads();
    {
      float v;
      if (c == 0) v = 0.03125f;
      else {
        unsigned h = (unsigned)t*1664525u + (unsigned)c*1013904223u + 12345u;
        h ^= h >> 16; h *= 2246822519u; h ^= h >> 13; h *= 3266489917u; h ^= h >> 16;
        v = ((float)(h & 0xFFFFFFu)/16777216.f) - 0.5f;
      }
      xb[t] = v;
    }
    __syncthreads();
    DEFL(0);
    int cu = 0;
    for (int round = 0; round < ROUNDS; round++) {
      if (t == 0) {
        double b = sB_, a = sA_;
        double e = 0.5*(b - a), cc = 0.5*(b + a);
        double s1 = e/(0.0 - cc);
        sCoef[0] = (float)(s1/e); sCoef[1] = (float)(-cc*(s1/e)); sCoef[2] = 0.f;
        double sp = s1;
        for (int k = 1; k < CHEB_M; k++) {
          double snn = 1.0/(2.0/s1 - sp);
          double a2 = 2.0*snn/e;
          sCoef[k*3] = (float)a2; sCoef[k*3+1] = (float)(-cc*a2); sCoef[k*3+2] = (float)(-sp*snn);
          sp = snn;
        }
      }
      __syncthreads();
      int pv_ = (cu+1)%3, nx = (cu+2)%3;
      for (int k = 0; k < CHEB_M; k++) {
        CHSTEP(cu, pv_, nx, sCoef[k*3], sCoef[k*3+1], sCoef[k*3+2]);
        int op = pv_; pv_ = cu; cu = nx; nx = op;
        if (k == 4 || k == 9 || k == CHEB_M-1) { DEFL(cu); DEFL(pv_); }
      }
      LMUL(cu);
      float* Xp = (round & 1) ? g_X1 : g_X0;
      Xp[c*N + t] = xb[cu*N + t];
      g_W[c*N + t] = wl[t];
      GBAR();                                      // X,W published
      GHROWS(Xp, cu);
      GBAR();                                      // G,Htilde complete
      for (int id = t; id < Q*Q; id += NTHR) sM3[id>>5][id&31] = g_H[id];
      CHOLINV();
      RRTRANS();
      if (round < ROUNDS-1) {
        POWA();
        MULR(Xp, 0); cu = 0;
      } else {
        JACOBI();
        SORTP();
        if (t < 256) {
          int k = t >> 3, cc2 = t & 7;
          int pc = sPerm[cc2];
          double a = 0.0;
          for (int m = 0; m < Q; m++) a += sM2[k][m]*sM1[m][pc];
          sFQ[k][cc2] = (float)a;
        }
        __syncthreads();
        if (c < 8) {
          float acc = 0.f;
          #pragma unroll
          for (int k = 0; k < Q; k++) acc += Xp[k*N + t]*sFQ[k][c];
          g_Fc[t*8 + c] = acc;
        }
        GBAR();                                    // F published
      }
    }
  };

  // ================= BUILD =================
  for (int s2 = 0; s2 < 2; s2++) {
    int r = c*32 + wv*2 + s2;
    int cnt = 0;
    for (int c0 = 0; c0 < N; c0 += 64) {
      int j = c0 + ln;
      float v = A[r*N + j];
      bool keep = (j != r) && (v > 0.f);
      unsigned long long m = __ballot(keep);
      int pos = __popcll(m & ((1ull << ln) - 1ull));
      if (keep) {
        int w = cnt + pos;
        if (w < W1) { g_idx1[r*W1 + w] = (unsigned short)j; g_a0[r*W1 + w] = v; }
        g_Sd[j*N + r] = v;
      }
      cnt += __popcll(m);
    }
    cnt = cnt < W1 ? cnt : W1;
    if (ln == 0) g_nnz1[r] = cnt;
    g_u[r*W1 + ln] = 1.f;
    g_s[r*W1 + ln] = 0.f;
  }
  GBAR();
  for (int s2 = 0; s2 < 2; s2++) {
    int r = c*32 + wv*2 + s2;
    int cnt = 0; float dacc = 0.f;
    for (int c0 = 0; c0 < N; c0 += 64) {
      int j = c0 + ln;
      float vr = A[r*N + j];
      float vc = g_Sd[r*N + j];
      bool keep = (j != r) && (vr > 0.f || vc > 0.f);
      unsigned long long m = __ballot(keep);
      int pos = __popcll(m & ((1ull << ln) - 1ull));
      if (keep) {
        int w = cnt + pos;
        if (w < W2S) {
          float val = 0.5f*(vr + vc);
          unsigned pv = packrw((unsigned)j, val);
          g_rowpT[w*N + r] = pv;
          g_jidx[r*W2S + w] = (unsigned short)j;
          g_w2[r*W2S + w] = val;
          g_w2fin[r*W2S + w] = val;
          dacc += unpackw(pv);
        }
      }
      cnt += __popcll(m);
    }
    for (int o = 32; o; o >>= 1) dacc += __shfl_xor(dacc, o);
    cnt = cnt < W2S ? cnt : W2S;
    int nz8 = (cnt + 7) & ~7; if (nz8 < 8) nz8 = 8;
    if (ln == 0) { g_nnz2[r] = cnt; g_nz8[r] = nz8; g_deg[r] = dacc; }
    for (int w = cnt + ln; w < W2S; w += 64) {
      g_rowpT[w*N + r] = ((unsigned)r) << 16;    // zero-weight padding
      g_w2[r*W2S + w] = 0.f;
      g_w2fin[r*W2S + w] = 0.f;
    }
    for (int j = ln; j < N; j += 64) g_Sd[r*N + j] = 0.f;
  }
  GBAR();

  // global padded max nnz (uniform loop bound for the chain)
  {
    int m = g_nz8[t];
    for (int o = 32; o; o >>= 1) { int v = __shfl_xor(m, o); m = v > m ? v : m; }
    if (ln == 0) sRedI[wv] = m;
    __syncthreads();
    if (t == 0) {
      int mm = 8;
      for (int w = 0; w < 16; w++) mm = sRedI[w] > mm ? sRedI[w] : mm;
      sKmax = mm;
      sLamV = 0.01f; sDoneV = 0;
    }
    __syncthreads();
  }

  // ================= initial eigensolve -> F =================
  EIG();
  if (t < 256) g_F[c*256 + t] = g_Fc[c*256 + t];
  GBAR();

  // ================= CLR iterations =================
  for (int iter = 0; iter < NITER; iter++) {
    if (t < 32) {
      int r = c*32 + t; float ss = 0.f;
      #pragma unroll
      for (int d = 0; d < 8; d++) { float v = g_F[r*8 + d]; ss += v*v; }
      g_sn[r] = ss;
    }
    GBAR();
    {
      float lamreg = sLamV;
      for (int s2 = 0; s2 < 2; s2++) {
        int r = c*32 + wv*2 + s2;
        int nnz = g_nnz1[r];
        bool valid = ln < nnz;
        int e = r*W1 + ln;
        int cidx = valid ? (int)g_idx1[e] : 0;
        float a0v = valid ? g_a0[e] : 0.f;
        float uu = valid ? g_u[e] : 1.f;
        float fr[8];
        #pragma unroll
        for (int d = 0; d < 8; d++) fr[d] = g_F[r*8 + d];
        float dot = 0.f;
        #pragma unroll
        for (int d = 0; d < 8; d++) dot += fr[d]*g_F[cidx*8 + d];
        float dist = fmaxf(g_sn[r] + g_sn[cidx] - 2.f*dot, 0.f);
        float dd = uu*a0v - 0.5f*lamreg*dist;
        float tmin = valid ? (uu - dd) : 3.0e38f;
        for (int o = 32; o; o >>= 1) tmin = fminf(tmin, __shfl_xor(tmin, o));
        float lam = (tmin < 3.0e38f) ? tmin : 0.f;
        for (int it = 0; it < NEWT; it++) {
          float v1 = (lam + dd)/uu;
          bool pos = valid && (v1 > 0.f);
          float gg = pos ? (1.f/uu) : 0.f;
          float ff = pos ? v1 : 0.f;
          for (int o = 32; o; o >>= 1) { gg += __shfl_xor(gg, o); ff += __shfl_xor(ff, o); }
          float f = ff - 1.f;
          float step = f/(gg > 0.f ? gg : 1.f);
          lam = (fabsf(f) > 1e-8f) ? (lam - step) : lam;
        }
        float v1 = (lam + dd)/uu;
        float sv = fmaxf(v1, 0.f);
        if (valid) {
          g_snew[e] = sv;
          float df = sv - a0v;
          g_unew[e] = 1.f/(2.f*sqrtf(df*df + 2.2204e-16f));
          g_Sd[r*N + cidx] = sv;
        }
      }
    }
    GBAR();
    for (int s2 = 0; s2 < 2; s2++) {
      int r = c*32 + wv*2 + s2;
      int nnz = g_nnz2[r];
      float dacc = 0.f;
      for (int k2 = ln; k2 < nnz; k2 += 64) {
        int j = (int)g_jidx[r*W2S + k2];
        float v = 0.5f*(g_Sd[r*N + j] + g_Sd[j*N + r]);
        unsigned np = packrw((unsigned)j, v);
        g_w2[r*W2S + k2] = v;
        g_rowpT[k2*N + r] = np;
        dacc += unpackw(np);
      }
      for (int o = 32; o; o >>= 1) dacc += __shfl_xor(dacc, o);
      if (ln == 0) g_deg[r] = dacc;
    }
    GBAR();
    if (iter < NITER-1) {
      EIG();
      if (t == 0) {
        double fn1 = 0.0;
        for (int i = 0; i < 8; i++) fn1 += sTheta[i];
        double fn2 = fn1 + sTheta[8];
        int done = sDoneV; float lam = sLamV;
        int c1 = (fn1 > 1e-10) ? 1 : 0;
        int c2 = ((!c1) && (fn2 < 1e-10)) ? 1 : 0;
        sF0 = !done;
        sF1 = (!done) && (!c2);
        if (!done) { if (c1) lam *= 2.f; else if (c2) lam *= 0.5f; sLamV = lam; }
        sDoneV = done || ((!c1) && (!c2));
      }
    } else {
      if (t == 0) { sF0 = !sDoneV; sF1 = 0; }
    }
    __syncthreads();
    if (sF0) {
      for (int k2 = t; k2 < 32*W1; k2 += NTHR) { int id = c*32*W1 + k2; g_s[id] = g_snew[id]; g_u[id] = g_unew[id]; }
      for (int k2 = t; k2 < 32*W2S; k2 += NTHR) { int id = c*32*W2S + k2; g_w2fin[id] = g_w2[id]; }
    }
    if (sF1) {
      if (t < 256) g_F[c*256 + t] = g_Fc[c*256 + t];
    }
    GBAR();
  }

  // ================= outputs: S =================
  for (int s2 = 0; s2 < 2; s2++) {
    int r = c*32 + wv*2 + s2;
    if (ln < g_nnz1[r]) out[N + r*N + (int)g_idx1[r*W1 + ln]] = g_s[r*W1 + ln];
  }

  // ================= connected components (block 0) =================
  if (c == 0) {
    sLab[t] = t;
    __syncthreads();
    for (int it2 = 0; it2 < CCIT; it2++) {
      int nnz = g_nnz2[t];
      int m = sLab[t];
      for (int k2 = 0; k2 < nnz; k2++) {
        if (g_w2fin[t*W2S + k2] > 0.f) {
          int l2 = sLab[(int)g_jidx[t*W2S + k2]];
          m = m < l2 ? m : l2;
        }
      }
      sLab2[t] = m;
      __syncthreads();
      sLab[t] = sLab2[sLab2[t]];
      __syncthreads();
    }
    out[t] = (float)sLab[t];
  }
}

extern "C" void kernel_launch(void* const* d_in, const int* in_sizes, int n_in,
                              void* d_out, int out_size, void* d_ws, size_t ws_size,
                              hipStream_t stream) {
  const float* A = (const float*)d_in[0];
  float* out = (float*)d_out;

  void *pSd, *pFlags, *pGen;
  hipGetSymbolAddress(&pSd,    HIP_SYMBOL(g_Sd));
  hipGetSymbolAddress(&pFlags, HIP_SYMBOL(g_flags));
  hipGetSymbolAddress(&pGen,   HIP_SYMBOL(g_gen));

  hipMemsetAsync(pSd, 0, sizeof(float)*(size_t)N*N, stream);
  hipMemsetAsync(pFlags, 0, sizeof(unsigned)*NB*32, stream);
  hipMemsetAsync(pGen, 0, sizeof(unsigned), stream);
  hipMemsetAsync(d_out, 0, sizeof(float)*(size_t)out_size, stream);

  mega<<<NB, NTHR, 0, stream>>>(A, out);
}

// Round 7
// 5979.733 us; speedup vs baseline: 1.2642x; 1.2642x over previous
//
#include <hip/hip_runtime.h>
#include <hip/hip_fp16.h>
#include <math.h>

#define N 1024
#define W1 64
#define W2S 96
#define Q 32
#define NB 32
#define NTHR 1024
#define CHEB_M 16
#define ROUNDS 3
#define NITER 6
#define NEWT 20
#define JSWEEPS 5
#define CCIT 12

#define WFENCE() asm volatile("" ::: "memory")

// ---------------- device state ----------------
__device__ unsigned g_flags[NB*32];
__device__ unsigned short g_idx1[N*W1];
__device__ float g_a0[N*W1], g_u[N*W1], g_unew[N*W1], g_s[N*W1], g_snew[N*W1];
__device__ int g_nnz1[N], g_nnz2[N], g_nz8[N];
__device__ unsigned g_rowpT[W2S*N];            // COLUMN-major packed: (idx<<16)|f16(w)
__device__ unsigned short g_jidx[N*W2S];       // row-major idx list
__device__ float g_w2[N*W2S], g_w2fin[N*W2S];
__device__ float g_deg[N], g_sn[N];
__device__ float g_Sd[N*N];
__device__ float g_X0[Q*N], g_X1[Q*N], g_W[Q*N];
__device__ double g_G[Q*Q], g_H[Q*Q];
__device__ float g_F[N*8], g_Fc[N*8];

__device__ __forceinline__ unsigned packrw(unsigned j, float w) {
  __half h = __float2half_rn(w);
  unsigned short bits; __builtin_memcpy(&bits, &h, 2);
  return (j << 16) | (unsigned)bits;
}
__device__ __forceinline__ float unpackw(unsigned v) {
  unsigned short bits = (unsigned short)(v & 0xFFFFu);
  __half h; __builtin_memcpy(&h, &bits, 2);
  return __half2float(h);
}

#define P1(pv) { unsigned _p = (pv); acc += __half2float(__ushort_as_half((unsigned short)(_p & 0xFFFFu))) * xc[_p >> 16]; }

__global__ __launch_bounds__(NTHR) void mega(const float* __restrict__ A, float* __restrict__ out) {
  const int c = blockIdx.x;
  const int t = threadIdx.x;
  const int wv = t >> 6, ln = t & 63;

  __shared__ float xv[3][N];
  __shared__ float wl[N];
  __shared__ float degl[N];
  __shared__ double sM1[Q][Q+1];
  __shared__ double sM2[Q][Q+1];
  __shared__ double sM3[Q][Q+1];
  __shared__ float sFQ[Q][8];
  __shared__ double sTheta[Q];
  __shared__ int   sPerm[Q];
  __shared__ float sCoef[CHEB_M*3];
  __shared__ float sRed[16];
  __shared__ int   sKw[16];
  __shared__ double sCs[16][2];
  __shared__ int   sPr[16], sQr[16];
  __shared__ int   sLab[N], sLab2[N];
  __shared__ float sB_, sA_, sLamV;
  __shared__ int   sDoneV, sF0, sF1;

  float* xb = &xv[0][0];
  unsigned bcnt = 0;

  // one-hop symmetric barrier: every block's wave 0 polls all 32 flag lines
  auto GBAR = [&]() {
    __syncthreads();
    ++bcnt;
    if (t < 64) {
      if (ln == 0) {
        __builtin_amdgcn_fence(__ATOMIC_RELEASE, "agent");
        __hip_atomic_store(&g_flags[c*32], bcnt, __ATOMIC_RELAXED, __HIP_MEMORY_SCOPE_AGENT);
      }
      for (;;) {
        unsigned v = bcnt;
        if (ln < NB)
          v = __hip_atomic_load(&g_flags[ln*32], __ATOMIC_RELAXED, __HIP_MEMORY_SCOPE_AGENT);
        if (__all(v >= bcnt)) break;
        __builtin_amdgcn_s_sleep(2);
      }
      if (ln == 0) __builtin_amdgcn_fence(__ATOMIC_ACQUIRE, "agent");
    }
    __syncthreads();
  };

  // coalesced column-major ELL row-dot: thread t owns row t; wave-uniform bound
  auto SPROW = [&](const float* __restrict__ xc) -> float {
    float acc = 0.f;
    const int kmax = sKw[wv];
    const unsigned* __restrict__ rp = g_rowpT + t;
    for (int k = 0; k < kmax; k += 8) {
      const unsigned* __restrict__ p = rp + k*N;
      unsigned a0 = p[0*N], a1 = p[1*N], a2 = p[2*N], a3 = p[3*N];
      unsigned a4 = p[4*N], a5 = p[5*N], a6 = p[6*N], a7 = p[7*N];
      P1(a0) P1(a1) P1(a2) P1(a3) P1(a4) P1(a5) P1(a6) P1(a7)
    }
    return acc;
  };

  auto CHSTEP = [&](int cu, int pv_, int nx, float al, float be, float ga) {
    const float* xc = xb + cu*N;
    float acc = SPROW(xc);
    float xr = xc[t];
    float o = al*(degl[t]*xr - acc) + be*xr;
    if (ga != 0.f) o += ga * xb[pv_*N + t];
    xb[nx*N + t] = o;
    __syncthreads();
  };

  auto LMUL = [&](int cu) {
    const float* xc = xb + cu*N;
    float acc = SPROW(xc);
    wl[t] = degl[t]*xc[t] - acc;
    __syncthreads();
  };

  auto DEFL = [&](int bu) {
    if (c == 0) {
      xb[bu*N + t] = 0.03125f;
    } else {
      float s = xb[bu*N + t];
      for (int o = 32; o; o >>= 1) s += __shfl_xor(s, o);
      if (ln == 0) sRed[wv] = s;
      __syncthreads();
      float tot = 0.f;
      #pragma unroll
      for (int w = 0; w < 16; w++) tot += sRed[w];
      xb[bu*N + t] -= tot / (float)N;
    }
    __syncthreads();
  };

  auto GHROWS = [&](const float* Xp, int cu) {
    const float* xc = xb + cu*N;
    for (int k = wv; k < Q; k += 16) {
      const float* mx = Xp + k*N;
      const float* mw = g_W + k*N;
      double pg = 0.0, ph = 0.0;
      for (int s = 0; s < 16; s++) {
        int i = ln + s*64;
        double xv_ = (double)xc[i];
        pg += xv_ * (double)mx[i];
        ph += xv_ * (double)mw[i];
      }
      for (int o = 32; o; o >>= 1) { pg += __shfl_xor(pg, o); ph += __shfl_xor(ph, o); }
      if (ln == 0) { g_G[c*Q + k] = pg; g_H[c*Q + k] = ph; }
    }
  };

  // wave-0-local Cholesky + R^-1 (lockstep; WFENCE = compiler ordering only)
  auto CHOLINV = [&]() {
    for (int id = t; id < Q*Q; id += NTHR) sM1[id>>5][id&31] = g_G[id];
    __syncthreads();
    if (wv == 0) {
      const int j = ln & 31;
      const bool lo = ln < 32;
      double fl;
      { double md = 0.0;
        for (int i = 0; i < Q; i++) md = fmax(md, sM1[i][i]);
        fl = md*1e-13 + 1e-280; }
      for (int k = 0; k < Q; k++) {
        double dkk = sM1[k][k]; if (!(dkk > fl)) dkk = fl;
        double rkk = sqrt(dkk);
        if (lo && j > k) sM1[k][j] /= rkk;
        if (ln == 0) sM1[k][k] = rkk;
        WFENCE();
        if (lo) {
          for (int i = k+1; i < Q; i++)
            if (j >= i) sM1[i][j] -= sM1[k][i]*sM1[k][j];
        }
        WFENCE();
      }
      if (lo) {
        for (int i = 0; i < Q; i++) sM2[i][j] = 0.0;
        sM2[j][j] = 1.0/sM1[j][j];
        for (int i = j-1; i >= 0; i--) {
          double sa = 0.0;
          for (int k2 = i+1; k2 <= j; k2++) sa += sM1[i][k2]*sM2[k2][j];
          sM2[i][j] = -sa/sM1[i][i];
        }
      }
    }
    __syncthreads();
  };

  auto RRTRANS = [&]() {   // sM3 = R^-T * sM3 * R^-1
    int i = t >> 5, j = t & 31;
    double a = 0.0;
    for (int k = 0; k <= i; k++) a += sM2[k][i]*sM3[k][j];
    __syncthreads();
    sM1[i][j] = a;
    __syncthreads();
    double b = 0.0;
    for (int k = 0; k <= j; k++) b += sM1[i][k]*sM2[k][j];
    __syncthreads();
    sM3[i][j] = b;
    __syncthreads();
  };

  auto MULR = [&](const float* Xp, int tb) {
    float acc = 0.f;
    #pragma unroll
    for (int k = 0; k < Q; k++) acc += Xp[k*N + t] * (float)sM2[k][c];
    xb[tb*N + t] = acc;
    __syncthreads();
  };

  auto POWA = [&]() {
    if (wv == 0) {
      int rl = ln & 31;
      double v = 1.0, w_ = 0.0, nrm = 1.0;
      for (int it = 0; it < 20; it++) {
        w_ = 0.0;
        for (int k2 = 0; k2 < Q; k2++) w_ += sM3[rl][k2]*__shfl(v, k2);
        nrm = 0.0;
        for (int k2 = 0; k2 < Q; k2++) { double wk = __shfl(w_, k2); nrm += wk*wk; }
        nrm = sqrt(nrm) + 1e-300;
        v = w_/nrm;
      }
      if (ln == 0) {
        float b = sB_;
        float a = (float)(nrm*1.1);
        if (a > 0.9f*b) a = 0.9f*b;
        if (a < 0.02f*b) a = 0.02f*b;
        sA_ = a;
      }
    }
    __syncthreads();
  };

  // wave-0-local Jacobi on sM3 (vectors accumulate in sM1)
  auto JACOBI = [&]() {
    for (int id = t; id < Q*Q; id += NTHR) sM1[id>>5][id&31] = ((id>>5) == (id&31)) ? 1.0 : 0.0;
    __syncthreads();
    if (wv == 0) {
      const int cj = ln & 31, half = ln >> 5;
      for (int sw = 0; sw < JSWEEPS; sw++) {
        for (int rr2 = 0; rr2 < 31; rr2++) {
          if (ln < 16) {
            int p, q;
            if (ln == 0) { p = 31; q = rr2 % 31; }
            else { p = (rr2 + ln) % 31; q = (rr2 + 31 - ln) % 31; }
            sPr[ln] = p; sQr[ln] = q;
            double app = sM3[p][p], aqq = sM3[q][q], apq = sM3[p][q];
            double cth, sth;
            if (fabs(apq) < 1e-280) { cth = 1.0; sth = 0.0; }
            else {
              double ta = (aqq - app)/(2.0*apq);
              double tt = (ta >= 0.0 ? 1.0 : -1.0)/(fabs(ta) + sqrt(1.0 + ta*ta));
              cth = 1.0/sqrt(1.0 + tt*tt); sth = tt*cth;
            }
            sCs[ln][0] = cth; sCs[ln][1] = sth;
          }
          WFENCE();
          #pragma unroll
          for (int s = 0; s < 8; s++) {
            int pi = 2*s + half;
            int p = sPr[pi], q = sQr[pi];
            double cth = sCs[pi][0], sth = sCs[pi][1];
            double hp = sM3[p][cj], hq = sM3[q][cj];
            sM3[p][cj] = cth*hp - sth*hq;
            sM3[q][cj] = sth*hp + cth*hq;
          }
          WFENCE();
          #pragma unroll
          for (int s = 0; s < 8; s++) {
            int pi = 2*s + half;
            int p = sPr[pi], q = sQr[pi];
            double cth = sCs[pi][0], sth = sCs[pi][1];
            double hp = sM3[cj][p], hq = sM3[cj][q];
            sM3[cj][p] = cth*hp - sth*hq;
            sM3[cj][q] = sth*hp + cth*hq;
            double vp = sM1[cj][p], vq = sM1[cj][q];
            sM1[cj][p] = cth*vp - sth*vq;
            sM1[cj][q] = sth*vp + cth*vq;
          }
          WFENCE();
        }
      }
      if (ln < Q) sTheta[ln] = sM3[ln][ln];
    }
    __syncthreads();
  };

  auto SORTP = [&]() {
    if (t == 0) {
      double th[Q]; int pm[Q];
      for (int i = 0; i < Q; i++) { th[i] = sTheta[i]; pm[i] = i; }
      for (int i = 1; i < Q; i++) {
        double x = th[i]; int px = pm[i]; int j = i - 1;
        while (j >= 0 && th[j] > x) { th[j+1] = th[j]; pm[j+1] = pm[j]; j--; }
        th[j+1] = x; pm[j+1] = px;
      }
      for (int i = 0; i < Q; i++) { sTheta[i] = th[i]; sPerm[i] = pm[i]; }
    }
    __syncthreads();
  };

  auto EIG = [&]() {
    degl[t] = g_deg[t];
    __syncthreads();
    float mx = degl[t];
    for (int o = 32; o; o >>= 1) mx = fmaxf(mx, __shfl_xor(mx, o));
    if (ln == 0) sRed[wv] = mx;
    __syncthreads();
    if (t == 0) {
      float mm = 0.f;
      for (int w = 0; w < 16; w++) mm = fmaxf(mm, sRed[w]);
      float b = fmaxf(2.02f*mm, 1e-3f) + 1e-6f;
      sB_ = b; sA_ = 0.5f*b;
    }
    __syncthreads();
    {
      float v;
      if (c == 0) v = 0.03125f;
      else {
        unsigned h = (unsigned)t*1664525u + (unsigned)c*1013904223u + 12345u;
        h ^= h >> 16; h *= 2246822519u; h ^= h >> 13; h *= 3266489917u; h ^= h >> 16;
        v = ((float)(h & 0xFFFFFFu)/16777216.f) - 0.5f;
      }
      xb[t] = v;
    }
    __syncthreads();
    DEFL(0);
    int cu = 0;
    for (int round = 0; round < ROUNDS; round++) {
      if (t == 0) {
        double b = sB_, a = sA_;
        double e = 0.5*(b - a), cc = 0.5*(b + a);
        double s1 = e/(0.0 - cc);
        sCoef[0] = (float)(s1/e); sCoef[1] = (float)(-cc*(s1/e)); sCoef[2] = 0.f;
        double sp = s1;
        for (int k = 1; k < CHEB_M; k++) {
          double snn = 1.0/(2.0/s1 - sp);
          double a2 = 2.0*snn/e;
          sCoef[k*3] = (float)a2; sCoef[k*3+1] = (float)(-cc*a2); sCoef[k*3+2] = (float)(-sp*snn);
          sp = snn;
        }
      }
      __syncthreads();
      int pv_ = (cu+1)%3, nx = (cu+2)%3;
      for (int k = 0; k < CHEB_M; k++) {
        CHSTEP(cu, pv_, nx, sCoef[k*3], sCoef[k*3+1], sCoef[k*3+2]);
        int op = pv_; pv_ = cu; cu = nx; nx = op;
        if (k == 4 || k == 9 || k == CHEB_M-1) { DEFL(cu); DEFL(pv_); }
      }
      LMUL(cu);
      float* Xp = (round & 1) ? g_X1 : g_X0;
      Xp[c*N + t] = xb[cu*N + t];
      g_W[c*N + t] = wl[t];
      GBAR();                                      // X,W published
      GHROWS(Xp, cu);
      GBAR();                                      // G,Htilde complete
      for (int id = t; id < Q*Q; id += NTHR) sM3[id>>5][id&31] = g_H[id];
      CHOLINV();
      RRTRANS();
      if (round < ROUNDS-1) {
        POWA();
        MULR(Xp, 0); cu = 0;
      } else {
        JACOBI();
        SORTP();
        if (t < 256) {
          int k = t >> 3, cc2 = t & 7;
          int pc = sPerm[cc2];
          double a = 0.0;
          for (int m = 0; m < Q; m++) a += sM2[k][m]*sM1[m][pc];
          sFQ[k][cc2] = (float)a;
        }
        __syncthreads();
        if (c < 8) {
          float acc = 0.f;
          #pragma unroll
          for (int k = 0; k < Q; k++) acc += Xp[k*N + t]*sFQ[k][c];
          g_Fc[t*8 + c] = acc;
        }
        GBAR();                                    // F published
      }
    }
  };

  // ================= BUILD =================
  for (int s2 = 0; s2 < 2; s2++) {
    int r = c*32 + wv*2 + s2;
    int cnt = 0;
    for (int c0 = 0; c0 < N; c0 += 64) {
      int j = c0 + ln;
      float v = A[r*N + j];
      bool keep = (j != r) && (v > 0.f);
      unsigned long long m = __ballot(keep);
      int pos = __popcll(m & ((1ull << ln) - 1ull));
      if (keep) {
        int w = cnt + pos;
        if (w < W1) { g_idx1[r*W1 + w] = (unsigned short)j; g_a0[r*W1 + w] = v; }
        g_Sd[j*N + r] = v;
      }
      cnt += __popcll(m);
    }
    cnt = cnt < W1 ? cnt : W1;
    if (ln == 0) g_nnz1[r] = cnt;
    g_u[r*W1 + ln] = 1.f;
    g_s[r*W1 + ln] = 0.f;
  }
  GBAR();
  for (int s2 = 0; s2 < 2; s2++) {
    int r = c*32 + wv*2 + s2;
    int cnt = 0; float dacc = 0.f;
    for (int c0 = 0; c0 < N; c0 += 64) {
      int j = c0 + ln;
      float vr = A[r*N + j];
      float vc = g_Sd[r*N + j];
      bool keep = (j != r) && (vr > 0.f || vc > 0.f);
      unsigned long long m = __ballot(keep);
      int pos = __popcll(m & ((1ull << ln) - 1ull));
      if (keep) {
        int w = cnt + pos;
        if (w < W2S) {
          float val = 0.5f*(vr + vc);
          unsigned pv = packrw((unsigned)j, val);
          g_rowpT[w*N + r] = pv;
          g_jidx[r*W2S + w] = (unsigned short)j;
          g_w2[r*W2S + w] = val;
          g_w2fin[r*W2S + w] = val;
          dacc += unpackw(pv);
        }
      }
      cnt += __popcll(m);
    }
    for (int o = 32; o; o >>= 1) dacc += __shfl_xor(dacc, o);
    cnt = cnt < W2S ? cnt : W2S;
    int nz8 = (cnt + 7) & ~7; if (nz8 < 8) nz8 = 8;
    if (ln == 0) { g_nnz2[r] = cnt; g_nz8[r] = nz8; g_deg[r] = dacc; }
    for (int w = cnt + ln; w < W2S; w += 64) {
      g_rowpT[w*N + r] = ((unsigned)r) << 16;    // zero-weight padding
      g_w2[r*W2S + w] = 0.f;
      g_w2fin[r*W2S + w] = 0.f;
    }
    for (int j = ln; j < N; j += 64) g_Sd[r*N + j] = 0.f;
  }
  GBAR();

  // per-wave static padded-nnz bound (thread t owns row t in the chain)
  {
    int m = g_nz8[t];
    for (int o = 32; o; o >>= 1) { int v = __shfl_xor(m, o); m = v > m ? v : m; }
    if (ln == 0) sKw[wv] = m;
    if (t == 0) { sLamV = 0.01f; sDoneV = 0; }
    __syncthreads();
  }

  // ================= initial eigensolve -> F =================
  EIG();
  if (t < 256) g_F[c*256 + t] = g_Fc[c*256 + t];
  GBAR();

  // ================= CLR iterations =================
  for (int iter = 0; iter < NITER; iter++) {
    if (t < 32) {
      int r = c*32 + t; float ss = 0.f;
      #pragma unroll
      for (int d = 0; d < 8; d++) { float v = g_F[r*8 + d]; ss += v*v; }
      g_sn[r] = ss;
    }
    GBAR();
    {
      float lamreg = sLamV;
      for (int s2 = 0; s2 < 2; s2++) {
        int r = c*32 + wv*2 + s2;
        int nnz = g_nnz1[r];
        bool valid = ln < nnz;
        int e = r*W1 + ln;
        int cidx = valid ? (int)g_idx1[e] : 0;
        float a0v = valid ? g_a0[e] : 0.f;
        float uu = valid ? g_u[e] : 1.f;
        float fr[8];
        #pragma unroll
        for (int d = 0; d < 8; d++) fr[d] = g_F[r*8 + d];
        float dot = 0.f;
        #pragma unroll
        for (int d = 0; d < 8; d++) dot += fr[d]*g_F[cidx*8 + d];
        float dist = fmaxf(g_sn[r] + g_sn[cidx] - 2.f*dot, 0.f);
        float dd = uu*a0v - 0.5f*lamreg*dist;
        float tmin = valid ? (uu - dd) : 3.0e38f;
        for (int o = 32; o; o >>= 1) tmin = fminf(tmin, __shfl_xor(tmin, o));
        float lam = (tmin < 3.0e38f) ? tmin : 0.f;
        for (int it = 0; it < NEWT; it++) {
          float v1 = (lam + dd)/uu;
          bool pos = valid && (v1 > 0.f);
          float gg = pos ? (1.f/uu) : 0.f;
          float ff = pos ? v1 : 0.f;
          for (int o = 32; o; o >>= 1) { gg += __shfl_xor(gg, o); ff += __shfl_xor(ff, o); }
          float f = ff - 1.f;
          float step = f/(gg > 0.f ? gg : 1.f);
          lam = (fabsf(f) > 1e-8f) ? (lam - step) : lam;
        }
        float v1 = (lam + dd)/uu;
        float sv = fmaxf(v1, 0.f);
        if (valid) {
          g_snew[e] = sv;
          float df = sv - a0v;
          g_unew[e] = 1.f/(2.f*sqrtf(df*df + 2.2204e-16f));
          g_Sd[r*N + cidx] = sv;
        }
      }
    }
    GBAR();
    for (int s2 = 0; s2 < 2; s2++) {
      int r = c*32 + wv*2 + s2;
      int nnz = g_nnz2[r];
      float dacc = 0.f;
      for (int k2 = ln; k2 < nnz; k2 += 64) {
        int j = (int)g_jidx[r*W2S + k2];
        float v = 0.5f*(g_Sd[r*N + j] + g_Sd[j*N + r]);
        unsigned np = packrw((unsigned)j, v);
        g_w2[r*W2S + k2] = v;
        g_rowpT[k2*N + r] = np;
        dacc += unpackw(np);
      }
      for (int o = 32; o; o >>= 1) dacc += __shfl_xor(dacc, o);
      if (ln == 0) g_deg[r] = dacc;
    }
    GBAR();
    if (iter < NITER-1) {
      EIG();
      if (t == 0) {
        double fn1 = 0.0;
        for (int i = 0; i < 8; i++) fn1 += sTheta[i];
        double fn2 = fn1 + sTheta[8];
        int done = sDoneV; float lam = sLamV;
        int c1 = (fn1 > 1e-10) ? 1 : 0;
        int c2 = ((!c1) && (fn2 < 1e-10)) ? 1 : 0;
        sF0 = !done;
        sF1 = (!done) && (!c2);
        if (!done) { if (c1) lam *= 2.f; else if (c2) lam *= 0.5f; sLamV = lam; }
        sDoneV = done || ((!c1) && (!c2));
      }
    } else {
      if (t == 0) { sF0 = !sDoneV; sF1 = 0; }
    }
    __syncthreads();
    if (sF0) {
      for (int k2 = t; k2 < 32*W1; k2 += NTHR) { int id = c*32*W1 + k2; g_s[id] = g_snew[id]; g_u[id] = g_unew[id]; }
      for (int k2 = t; k2 < 32*W2S; k2 += NTHR) { int id = c*32*W2S + k2; g_w2fin[id] = g_w2[id]; }
    }
    if (sF1) {
      if (t < 256) g_F[c*256 + t] = g_Fc[c*256 + t];
    }
    GBAR();
  }

  // ================= outputs: S =================
  for (int s2 = 0; s2 < 2; s2++) {
    int r = c*32 + wv*2 + s2;
    if (ln < g_nnz1[r]) out[N + r*N + (int)g_idx1[r*W1 + ln]] = g_s[r*W1 + ln];
  }

  // ================= connected components (block 0) =================
  if (c == 0) {
    sLab[t] = t;
    __syncthreads();
    for (int it2 = 0; it2 < CCIT; it2++) {
      int nnz = g_nnz2[t];
      int m = sLab[t];
      for (int k2 = 0; k2 < nnz; k2++) {
        if (g_w2fin[t*W2S + k2] > 0.f) {
          int l2 = sLab[(int)g_jidx[t*W2S + k2]];
          m = m < l2 ? m : l2;
        }
      }
      sLab2[t] = m;
      __syncthreads();
      sLab[t] = sLab2[sLab2[t]];
      __syncthreads();
    }
    out[t] = (float)sLab[t];
  }
}

extern "C" void kernel_launch(void* const* d_in, const int* in_sizes, int n_in,
                              void* d_out, int out_size, void* d_ws, size_t ws_size,
                              hipStream_t stream) {
  const float* A = (const float*)d_in[0];
  float* out = (float*)d_out;

  void *pSd, *pFlags;
  hipGetSymbolAddress(&pSd,    HIP_SYMBOL(g_Sd));
  hipGetSymbolAddress(&pFlags, HIP_SYMBOL(g_flags));

  hipMemsetAsync(pSd, 0, sizeof(float)*(size_t)N*N, stream);
  hipMemsetAsync(pFlags, 0, sizeof(unsigned)*NB*32, stream);
  hipMemsetAsync(d_out, 0, sizeof(float)*(size_t)out_size, stream);

  mega<<<NB, NTHR, 0, stream>>>(A, out);
}

// Round 10
// 5186.262 us; speedup vs baseline: 1.4577x; 1.1530x over previous
//
#include <hip/hip_runtime.h>
#include <hip/hip_fp16.h>
#include <math.h>

#define N 1024
#define W1 64
#define W2S 96
#define Q 32
#define NB 32
#define NTHR 1024
#define CHEB_M 16
#define ROUNDS_COLD 3
#define ROUNDS_WARM 2
#define NITER 6
#define NEWT 20
#define JSWEEPS 5
#define CCIT 12

#define WFENCE() asm volatile("" ::: "memory")

// ---------------- device state ----------------
__device__ unsigned g_flags[NB*32];
__device__ unsigned short g_idx1[N*W1];
__device__ float g_a0[N*W1], g_u[N*W1], g_unew[N*W1], g_s[N*W1], g_snew[N*W1];
__device__ int g_nnz1[N], g_nnz2[N], g_nz8[N];
__device__ unsigned g_rowpT[W2S*N];            // COLUMN-major packed: (idx<<16)|f16(w)
__device__ unsigned short g_jidx[N*W2S];       // row-major idx list
__device__ float g_w2[N*W2S], g_w2fin[N*W2S];
__device__ float g_deg[N], g_sn[N];
__device__ float g_Sd[N*N];
__device__ float g_X0[Q*N], g_X1[Q*N], g_W[Q*N];
__device__ double g_G[Q*Q], g_H[Q*Q];
__device__ float g_F[N*8], g_Fc[N*8];

__device__ __forceinline__ unsigned packrw(unsigned j, float w) {
  __half h = __float2half_rn(w);
  unsigned short bits; __builtin_memcpy(&bits, &h, 2);
  return (j << 16) | (unsigned)bits;
}
__device__ __forceinline__ float unpackw(unsigned v) {
  unsigned short bits = (unsigned short)(v & 0xFFFFu);
  __half h; __builtin_memcpy(&h, &bits, 2);
  return __half2float(h);
}

#define P1(acc, pv) { unsigned _p = (pv); acc += __half2float(__ushort_as_half((unsigned short)(_p & 0xFFFFu))) * xc[_p >> 16]; }

__global__ __launch_bounds__(NTHR) void mega(const float* __restrict__ A, float* __restrict__ out) {
  const int c = blockIdx.x;
  const int t = threadIdx.x;
  const int wv = t >> 6, ln = t & 63;

  __shared__ float xv[3][N];
  __shared__ float wl[N];
  __shared__ float degl[N];
  __shared__ double sM1[Q][Q+1];
  __shared__ double sM2[Q][Q+1];
  __shared__ double sM3[Q][Q+1];
  __shared__ double sTheta[Q];
  __shared__ int   sPerm[Q];
  __shared__ float sCoef[CHEB_M*3];
  __shared__ float sRed[16];
  __shared__ int   sKw[16];
  __shared__ double sCs[16][2];
  __shared__ int   sPr[16], sQr[16];
  __shared__ int   sLab[N], sLab2[N];
  __shared__ float sB_, sA_, sLamV;
  __shared__ int   sDoneV, sF0, sF1;

  float* xb = &xv[0][0];
  unsigned bcnt = 0;
  int cur = 1;   // after each publish (P = cur?X0:X1; cur^=1), (cur?X1:X0) = last published

  // one-hop symmetric barrier: every block's wave 0 polls all 32 flag lines
  auto GBAR = [&]() {
    __syncthreads();
    ++bcnt;
    if (t < 64) {
      if (ln == 0) {
        __builtin_amdgcn_fence(__ATOMIC_RELEASE, "agent");
        __hip_atomic_store(&g_flags[c*32], bcnt, __ATOMIC_RELAXED, __HIP_MEMORY_SCOPE_AGENT);
      }
      for (;;) {
        unsigned v = bcnt;
        if (ln < NB)
          v = __hip_atomic_load(&g_flags[ln*32], __ATOMIC_RELAXED, __HIP_MEMORY_SCOPE_AGENT);
        if (__all(v >= bcnt)) break;
        __builtin_amdgcn_s_sleep(2);
      }
      if (ln == 0) __builtin_amdgcn_fence(__ATOMIC_ACQUIRE, "agent");
    }
    __syncthreads();
  };

  // coalesced column-major ELL row-dot: thread t owns row t; wave-uniform bound
  auto SPROW = [&](const float* __restrict__ xc) -> float {
    float acc = 0.f, acc2 = 0.f;
    const int kmax = sKw[wv];
    const unsigned* __restrict__ rp = g_rowpT + t;
    for (int k = 0; k < kmax; k += 8) {
      const unsigned* __restrict__ p = rp + k*N;
      unsigned a0 = p[0*N], a1 = p[1*N], a2 = p[2*N], a3 = p[3*N];
      unsigned a4 = p[4*N], a5 = p[5*N], a6 = p[6*N], a7 = p[7*N];
      P1(acc, a0) P1(acc2, a1) P1(acc, a2) P1(acc2, a3)
      P1(acc, a4) P1(acc2, a5) P1(acc, a6) P1(acc2, a7)
    }
    return acc + acc2;
  };

  auto CHSTEP = [&](int cu_, int pv_, int nx, float al, float be, float ga) {
    const float* xc = xb + cu_*N;
    float acc = SPROW(xc);
    float xr = xc[t];
    float o = al*(degl[t]*xr - acc) + be*xr;
    if (ga != 0.f) o += ga * xb[pv_*N + t];
    xb[nx*N + t] = o;
    __syncthreads();
  };

  auto LMUL = [&](int cu_) {
    const float* xc = xb + cu_*N;
    float acc = SPROW(xc);
    wl[t] = degl[t]*xc[t] - acc;
    __syncthreads();
  };

  auto DEFL = [&](int bu) {
    if (c == 0) {
      xb[bu*N + t] = 0.03125f;
    } else {
      float s = xb[bu*N + t];
      for (int o = 32; o; o >>= 1) s += __shfl_xor(s, o);
      if (ln == 0) sRed[wv] = s;
      __syncthreads();
      float tot = 0.f;
      #pragma unroll
      for (int w = 0; w < 16; w++) tot += sRed[w];
      xb[bu*N + t] -= tot / (float)N;
    }
    __syncthreads();
  };

  auto GHROWS = [&](const float* Xp, int cu_) {
    const float* xc = xb + cu_*N;
    for (int k = wv; k < Q; k += 16) {
      const float* mx = Xp + k*N;
      const float* mw = g_W + k*N;
      double pg = 0.0, ph = 0.0;
      for (int s = 0; s < 16; s++) {
        int i = ln + s*64;
        double xv_ = (double)xc[i];
        pg += xv_ * (double)mx[i];
        ph += xv_ * (double)mw[i];
      }
      for (int o = 32; o; o >>= 1) { pg += __shfl_xor(pg, o); ph += __shfl_xor(ph, o); }
      if (ln == 0) { g_G[c*Q + k] = pg; g_H[c*Q + k] = ph; }
    }
  };

  // wave-0-local Cholesky + R^-1 (lockstep; WFENCE = compiler ordering only)
  auto CHOLINV = [&]() {
    for (int id = t; id < Q*Q; id += NTHR) sM1[id>>5][id&31] = g_G[id];
    __syncthreads();
    if (wv == 0) {
      const int j = ln & 31;
      const bool lo = ln < 32;
      double fl;
      { double md = 0.0;
        for (int i = 0; i < Q; i++) md = fmax(md, sM1[i][i]);
        fl = md*1e-13 + 1e-280; }
      for (int k = 0; k < Q; k++) {
        double dkk = sM1[k][k]; if (!(dkk > fl)) dkk = fl;
        double rkk = sqrt(dkk);
        if (lo && j > k) sM1[k][j] /= rkk;
        if (ln == 0) sM1[k][k] = rkk;
        WFENCE();
        if (lo) {
          for (int i = k+1; i < Q; i++)
            if (j >= i) sM1[i][j] -= sM1[k][i]*sM1[k][j];
        }
        WFENCE();
      }
      if (lo) {
        for (int i = 0; i < Q; i++) sM2[i][j] = 0.0;
        sM2[j][j] = 1.0/sM1[j][j];
        for (int i = j-1; i >= 0; i--) {
          double sa = 0.0;
          for (int k2 = i+1; k2 <= j; k2++) sa += sM1[i][k2]*sM2[k2][j];
          sM2[i][j] = -sa/sM1[i][i];
        }
      }
    }
    __syncthreads();
  };

  auto RRTRANS = [&]() {   // sM3 = R^-T * sM3 * R^-1
    int i = t >> 5, j = t & 31;
    double a = 0.0;
    for (int k = 0; k <= i; k++) a += sM2[k][i]*sM3[k][j];
    __syncthreads();
    sM1[i][j] = a;
    __syncthreads();
    double b = 0.0;
    for (int k = 0; k <= j; k++) b += sM1[i][k]*sM2[k][j];
    __syncthreads();
    sM3[i][j] = b;
    __syncthreads();
  };

  auto MULR = [&](const float* Xp, int tb) {   // xb[tb] = Xp * R^-1[:,c]  (orthonormal col)
    float acc = 0.f;
    #pragma unroll
    for (int k = 0; k < Q; k++) acc += Xp[k*N + t] * (float)sM2[k][c];
    xb[tb*N + t] = acc;
    __syncthreads();
  };

  auto POWA = [&]() {
    if (wv == 0) {
      int rl = ln & 31;
      double v = 1.0, w_ = 0.0, nrm = 1.0;
      for (int it = 0; it < 20; it++) {
        w_ = 0.0;
        for (int k2 = 0; k2 < Q; k2++) w_ += sM3[rl][k2]*__shfl(v, k2);
        nrm = 0.0;
        for (int k2 = 0; k2 < Q; k2++) { double wk = __shfl(w_, k2); nrm += wk*wk; }
        nrm = sqrt(nrm) + 1e-300;
        v = w_/nrm;
      }
      if (ln == 0) {
        float b = sB_;
        float a = (float)(nrm*1.1);
        if (a > 0.9f*b) a = 0.9f*b;
        if (a < 0.02f*b) a = 0.02f*b;
        sA_ = a;
      }
    }
    __syncthreads();
  };

  // wave-0-local Jacobi on sM3 (vectors accumulate in sM1)
  auto JACOBI = [&]() {
    for (int id = t; id < Q*Q; id += NTHR) sM1[id>>5][id&31] = ((id>>5) == (id&31)) ? 1.0 : 0.0;
    __syncthreads();
    if (wv == 0) {
      const int cj = ln & 31, half = ln >> 5;
      for (int sw = 0; sw < JSWEEPS; sw++) {
        for (int rr2 = 0; rr2 < 31; rr2++) {
          if (ln < 16) {
            int p, q;
            if (ln == 0) { p = 31; q = rr2 % 31; }
            else { p = (rr2 + ln) % 31; q = (rr2 + 31 - ln) % 31; }
            sPr[ln] = p; sQr[ln] = q;
            double app = sM3[p][p], aqq = sM3[q][q], apq = sM3[p][q];
            double cth, sth;
            if (fabs(apq) < 1e-280) { cth = 1.0; sth = 0.0; }
            else {
              double ta = (aqq - app)/(2.0*apq);
              double tt = (ta >= 0.0 ? 1.0 : -1.0)/(fabs(ta) + sqrt(1.0 + ta*ta));
              cth = 1.0/sqrt(1.0 + tt*tt); sth = tt*cth;
            }
            sCs[ln][0] = cth; sCs[ln][1] = sth;
          }
          WFENCE();
          #pragma unroll
          for (int s = 0; s < 8; s++) {
            int pi = 2*s + half;
            int p = sPr[pi], q = sQr[pi];
            double cth = sCs[pi][0], sth = sCs[pi][1];
            double hp = sM3[p][cj], hq = sM3[q][cj];
            sM3[p][cj] = cth*hp - sth*hq;
            sM3[q][cj] = sth*hp + cth*hq;
          }
          WFENCE();
          #pragma unroll
          for (int s = 0; s < 8; s++) {
            int pi = 2*s + half;
            int p = sPr[pi], q = sQr[pi];
            double cth = sCs[pi][0], sth = sCs[pi][1];
            double hp = sM3[cj][p], hq = sM3[cj][q];
            sM3[cj][p] = cth*hp - sth*hq;
            sM3[cj][q] = sth*hp + cth*hq;
            double vp = sM1[cj][p], vq = sM1[cj][q];
            sM1[cj][p] = cth*vp - sth*vq;
            sM1[cj][q] = sth*vp + cth*vq;
          }
          WFENCE();
        }
      }
      if (ln < Q) sTheta[ln] = sM3[ln][ln];
    }
    __syncthreads();
  };

  auto SORTP = [&]() {
    if (t == 0) {
      double th[Q]; int pm[Q];
      for (int i = 0; i < Q; i++) { th[i] = sTheta[i]; pm[i] = i; }
      for (int i = 1; i < Q; i++) {
        double x = th[i]; int px = pm[i]; int j = i - 1;
        while (j >= 0 && th[j] > x) { th[j+1] = th[j]; pm[j+1] = pm[j]; j--; }
        th[j+1] = x; pm[j+1] = px;
      }
      for (int i = 0; i < Q; i++) { sTheta[i] = th[i]; sPerm[i] = pm[i]; }
    }
    __syncthreads();
  };

  auto EIG = [&](int nrounds, bool warm) {
    degl[t] = g_deg[t];
    __syncthreads();
    float mx = degl[t];
    for (int o = 32; o; o >>= 1) mx = fmaxf(mx, __shfl_xor(mx, o));
    if (ln == 0) sRed[wv] = mx;
    __syncthreads();
    if (t == 0) {
      float mm = 0.f;
      for (int w = 0; w < 16; w++) mm = fmaxf(mm, sRed[w]);
      float b = fmaxf(2.02f*mm, 1e-3f) + 1e-6f;
      sB_ = b; sA_ = 0.5f*b;
    }
    __syncthreads();
    {
      float v;
      if (c == 0) v = 0.03125f;
      else if (warm) v = (cur ? g_X1 : g_X0)[c*N + t];  // last published = ORTHONORMAL Y
      else {
        unsigned h = (unsigned)t*1664525u + (unsigned)c*1013904223u + 12345u;
        h ^= h >> 16; h *= 2246822519u; h ^= h >> 13; h *= 3266489917u; h ^= h >> 16;
        v = ((float)(h & 0xFFFFFFu)/16777216.f) - 0.5f;
      }
      xb[t] = v;
    }
    __syncthreads();
    DEFL(0);
    int cu = 0;
    for (int round = 0; round < nrounds; round++) {
      if (t == 0) {
        double b = sB_, a = sA_;
        double e = 0.5*(b - a), cc = 0.5*(b + a);
        double s1 = e/(0.0 - cc);
        sCoef[0] = (float)(s1/e); sCoef[1] = (float)(-cc*(s1/e)); sCoef[2] = 0.f;
        double sp = s1;
        for (int k = 1; k < CHEB_M; k++) {
          double snn = 1.0/(2.0/s1 - sp);
          double a2 = 2.0*snn/e;
          sCoef[k*3] = (float)a2; sCoef[k*3+1] = (float)(-cc*a2); sCoef[k*3+2] = (float)(-sp*snn);
          sp = snn;
        }
      }
      __syncthreads();
      int pv_ = (cu+1)%3, nx = (cu+2)%3;
      for (int k = 0; k < CHEB_M; k++) {
        CHSTEP(cu, pv_, nx, sCoef[k*3], sCoef[k*3+1], sCoef[k*3+2]);
        int op = pv_; pv_ = cu; cu = nx; nx = op;
        if (k == 4 || k == 9 || k == CHEB_M-1) { DEFL(cu); DEFL(pv_); }
      }
      LMUL(cu);
      float* Xp = (cur ? g_X0 : g_X1);   // publish raw filtered basis
      cur ^= 1;
      Xp[c*N + t] = xb[cu*N + t];
      g_W[c*N + t] = wl[t];
      GBAR();                                      // X,W published
      GHROWS(Xp, cu);
      GBAR();                                      // G,Htilde complete
      for (int id = t; id < Q*Q; id += NTHR) sM3[id>>5][id&31] = g_H[id];
      CHOLINV();
      RRTRANS();
      if (round < nrounds-1) {
        POWA();
        MULR(Xp, 0); cu = 0;
      } else {
        JACOBI();
        SORTP();
        MULR(Xp, 0);                               // xb0 = own ORTHONORMAL column Y_c
        float* Yp = (cur ? g_X0 : g_X1);           // publish Y for future warm starts
        cur ^= 1;
        Yp[c*N + t] = xb[t];
        GBAR();                                    // Y published
        if (c < 8) {                               // F = Y * V[:,perm(c)]
          int pc = sPerm[c];
          float acc = 0.f;
          #pragma unroll
          for (int k = 0; k < Q; k++) acc += Yp[k*N + t] * (float)sM1[k][pc];
          g_Fc[t*8 + c] = acc;
        }
        GBAR();                                    // F published
      }
    }
  };

  // ================= BUILD =================
  for (int s2 = 0; s2 < 2; s2++) {
    int r = c*32 + wv*2 + s2;
    int cnt = 0;
    for (int c0 = 0; c0 < N; c0 += 64) {
      int j = c0 + ln;
      float v = A[r*N + j];
      bool keep = (j != r) && (v > 0.f);
      unsigned long long m = __ballot(keep);
      int pos = __popcll(m & ((1ull << ln) - 1ull));
      if (keep) {
        int w = cnt + pos;
        if (w < W1) { g_idx1[r*W1 + w] = (unsigned short)j; g_a0[r*W1 + w] = v; }
        g_Sd[j*N + r] = v;
      }
      cnt += __popcll(m);
    }
    cnt = cnt < W1 ? cnt : W1;
    if (ln == 0) g_nnz1[r] = cnt;
    g_u[r*W1 + ln] = 1.f;
    g_s[r*W1 + ln] = 0.f;
  }
  GBAR();
  for (int s2 = 0; s2 < 2; s2++) {
    int r = c*32 + wv*2 + s2;
    int cnt = 0; float dacc = 0.f;
    for (int c0 = 0; c0 < N; c0 += 64) {
      int j = c0 + ln;
      float vr = A[r*N + j];
      float vc = g_Sd[r*N + j];
      bool keep = (j != r) && (vr > 0.f || vc > 0.f);
      unsigned long long m = __ballot(keep);
      int pos = __popcll(m & ((1ull << ln) - 1ull));
      if (keep) {
        int w = cnt + pos;
        if (w < W2S) {
          float val = 0.5f*(vr + vc);
          unsigned pv = packrw((unsigned)j, val);
          g_rowpT[w*N + r] = pv;
          g_jidx[r*W2S + w] = (unsigned short)j;
          g_w2[r*W2S + w] = val;
          g_w2fin[r*W2S + w] = val;
          dacc += unpackw(pv);
        }
      }
      cnt += __popcll(m);
    }
    for (int o = 32; o; o >>= 1) dacc += __shfl_xor(dacc, o);
    cnt = cnt < W2S ? cnt : W2S;
    int nz8 = (cnt + 7) & ~7; if (nz8 < 8) nz8 = 8;
    if (ln == 0) { g_nnz2[r] = cnt; g_nz8[r] = nz8; g_deg[r] = dacc; }
    for (int w = cnt + ln; w < W2S; w += 64) {
      g_rowpT[w*N + r] = ((unsigned)r) << 16;    // zero-weight padding
      g_w2[r*W2S + w] = 0.f;
      g_w2fin[r*W2S + w] = 0.f;
    }
    for (int j = ln; j < N; j += 64) g_Sd[r*N + j] = 0.f;
  }
  GBAR();

  // per-wave static padded-nnz bound (thread t owns row t in the chain)
  {
    int m = g_nz8[t];
    for (int o = 32; o; o >>= 1) { int v = __shfl_xor(m, o); m = v > m ? v : m; }
    if (ln == 0) sKw[wv] = m;
    if (t == 0) { sLamV = 0.01f; sDoneV = 0; }
    __syncthreads();
  }

  // ================= initial (cold) eigensolve -> F, sn =================
  EIG(ROUNDS_COLD, false);
  if (t < 256) g_F[c*256 + t] = g_Fc[c*256 + t];
  __syncthreads();
  if (t < 32) {
    int r = c*32 + t; float ss = 0.f;
    #pragma unroll
    for (int d = 0; d < 8; d++) { float v = g_F[r*8 + d]; ss += v*v; }
    g_sn[r] = ss;
  }
  GBAR();

  // ================= CLR iterations =================
  for (int iter = 0; iter < NITER; iter++) {
    {
      float lamreg = sLamV;
      for (int s2 = 0; s2 < 2; s2++) {
        int r = c*32 + wv*2 + s2;
        int nnz = g_nnz1[r];
        bool valid = ln < nnz;
        int e = r*W1 + ln;
        int cidx = valid ? (int)g_idx1[e] : 0;
        float a0v = valid ? g_a0[e] : 0.f;
        float uu = valid ? g_u[e] : 1.f;
        float fr[8];
        #pragma unroll
        for (int d = 0; d < 8; d++) fr[d] = g_F[r*8 + d];
        float dot = 0.f;
        #pragma unroll
        for (int d = 0; d < 8; d++) dot += fr[d]*g_F[cidx*8 + d];
        float dist = fmaxf(g_sn[r] + g_sn[cidx] - 2.f*dot, 0.f);
        float dd = uu*a0v - 0.5f*lamreg*dist;
        float tmin = valid ? (uu - dd) : 3.0e38f;
        for (int o = 32; o; o >>= 1) tmin = fminf(tmin, __shfl_xor(tmin, o));
        float lam = (tmin < 3.0e38f) ? tmin : 0.f;
        for (int it = 0; it < NEWT; it++) {
          float v1 = (lam + dd)/uu;
          bool pos = valid && (v1 > 0.f);
          float gg = pos ? (1.f/uu) : 0.f;
          float ff = pos ? v1 : 0.f;
          for (int o = 32; o; o >>= 1) { gg += __shfl_xor(gg, o); ff += __shfl_xor(ff, o); }
          float f = ff - 1.f;
          float step = f/(gg > 0.f ? gg : 1.f);
          lam = (fabsf(f) > 1e-8f) ? (lam - step) : lam;
        }
        float v1 = (lam + dd)/uu;
        float sv = fmaxf(v1, 0.f);
        if (valid) {
          g_snew[e] = sv;
          float df = sv - a0v;
          g_unew[e] = 1.f/(2.f*sqrtf(df*df + 2.2204e-16f));
          g_Sd[r*N + cidx] = sv;
        }
      }
    }
    GBAR();
    for (int s2 = 0; s2 < 2; s2++) {
      int r = c*32 + wv*2 + s2;
      int nnz = g_nnz2[r];
      float dacc = 0.f;
      for (int k2 = ln; k2 < nnz; k2 += 64) {
        int j = (int)g_jidx[r*W2S + k2];
        float v = 0.5f*(g_Sd[r*N + j] + g_Sd[j*N + r]);
        unsigned np = packrw((unsigned)j, v);
        g_w2[r*W2S + k2] = v;
        g_rowpT[k2*N + r] = np;
        dacc += unpackw(np);
      }
      for (int o = 32; o; o >>= 1) dacc += __shfl_xor(dacc, o);
      if (ln == 0) g_deg[r] = dacc;
    }
    GBAR();
    if (iter < NITER-1) {
      // first in-loop solve spans the A->S operator change: full cold solve.
      // later solves see small incremental changes: warm 2-round solve from Y.
      if (iter == 0) EIG(ROUNDS_COLD, false);
      else           EIG(ROUNDS_WARM, true);
      if (t == 0) {
        double fn1 = 0.0;
        for (int i = 0; i < 8; i++) fn1 += sTheta[i];
        double fn2 = fn1 + sTheta[8];
        int done = sDoneV; float lam = sLamV;
        int c1 = (fn1 > 1e-10) ? 1 : 0;
        int c2 = ((!c1) && (fn2 < 1e-10)) ? 1 : 0;
        sF0 = !done;
        sF1 = (!done) && (!c2);
        if (!done) { if (c1) lam *= 2.f; else if (c2) lam *= 0.5f; sLamV = lam; }
        sDoneV = done || ((!c1) && (!c2));
      }
    } else {
      if (t == 0) { sF0 = !sDoneV; sF1 = 0; }
    }
    __syncthreads();
    if (sF0) {
      for (int k2 = t; k2 < 32*W1; k2 += NTHR) { int id = c*32*W1 + k2; g_s[id] = g_snew[id]; g_u[id] = g_unew[id]; }
      for (int k2 = t; k2 < 32*W2S; k2 += NTHR) { int id = c*32*W2S + k2; g_w2fin[id] = g_w2[id]; }
    }
    if (sF1) {
      if (t < 256) g_F[c*256 + t] = g_Fc[c*256 + t];
    }
    __syncthreads();
    if (t < 32) {                              // sn from (possibly updated) F
      int r = c*32 + t; float ss = 0.f;
      #pragma unroll
      for (int d = 0; d < 8; d++) { float v = g_F[r*8 + d]; ss += v*v; }
      g_sn[r] = ss;
    }
    GBAR();
  }

  // ================= outputs: S =================
  for (int s2 = 0; s2 < 2; s2++) {
    int r = c*32 + wv*2 + s2;
    if (ln < g_nnz1[r]) out[N + r*N + (int)g_idx1[r*W1 + ln]] = g_s[r*W1 + ln];
  }

  // ================= connected components (block 0) =================
  if (c == 0) {
    sLab[t] = t;
    __syncthreads();
    for (int it2 = 0; it2 < CCIT; it2++) {
      int nnz = g_nnz2[t];
      int m = sLab[t];
      for (int k2 = 0; k2 < nnz; k2++) {
        if (g_w2fin[t*W2S + k2] > 0.f) {
          int l2 = sLab[(int)g_jidx[t*W2S + k2]];
          m = m < l2 ? m : l2;
        }
      }
      sLab2[t] = m;
      __syncthreads();
      sLab[t] = sLab2[sLab2[t]];
      __syncthreads();
    }
    out[t] = (float)sLab[t];
  }
}

extern "C" void kernel_launch(void* const* d_in, const int* in_sizes, int n_in,
                              void* d_out, int out_size, void* d_ws, size_t ws_size,
                              hipStream_t stream) {
  const float* A = (const float*)d_in[0];
  float* out = (float*)d_out;

  void *pSd, *pFlags;
  hipGetSymbolAddress(&pSd,    HIP_SYMBOL(g_Sd));
  hipGetSymbolAddress(&pFlags, HIP_SYMBOL(g_flags));

  hipMemsetAsync(pSd, 0, sizeof(float)*(size_t)N*N, stream);
  hipMemsetAsync(pFlags, 0, sizeof(unsigned)*NB*32, stream);
  hipMemsetAsync(d_out, 0, sizeof(float)*(size_t)out_size, stream);

  mega<<<NB, NTHR, 0, stream>>>(A, out);
}

// Round 11
// 4474.425 us; speedup vs baseline: 1.6896x; 1.1591x over previous
//
#include <hip/hip_runtime.h>
#include <hip/hip_fp16.h>
#include <math.h>

#define N 1024
#define W1 64
#define W2S 96
#define Q 32
#define NB 32
#define NTHR 1024
#define CHEB_M 16
#define ROUNDS_COLD 3
#define ROUNDS_WARM 1
#define NITER 6
#define NEWT 20
#define JSWEEPS 5
#define CCIT 12

#define WFENCE() asm volatile("" ::: "memory")

// ---------------- device state ----------------
__device__ unsigned g_flags[NB*32];
__device__ unsigned short g_idx1[N*W1];
__device__ float g_a0[N*W1], g_u[N*W1], g_unew[N*W1], g_s[N*W1], g_snew[N*W1];
__device__ int g_nnz1[N], g_nnz2[N], g_nz8[N];
__device__ unsigned g_rowpT[W2S*N];            // COLUMN-major packed: (idx<<16)|f16(w)
__device__ unsigned short g_jidx[N*W2S];       // row-major idx list
__device__ float g_w2[N*W2S], g_w2fin[N*W2S];
__device__ float g_deg[N], g_sn[N];
__device__ float g_Sd[N*N];
__device__ float g_X0[Q*N], g_X1[Q*N], g_W[Q*N];
__device__ double g_G[Q*Q], g_H[Q*Q];
__device__ float g_F[N*8], g_Fc[N*8];

__device__ __forceinline__ unsigned packrw(unsigned j, float w) {
  __half h = __float2half_rn(w);
  unsigned short bits; __builtin_memcpy(&bits, &h, 2);
  return (j << 16) | (unsigned)bits;
}
__device__ __forceinline__ float unpackw(unsigned v) {
  unsigned short bits = (unsigned short)(v & 0xFFFFu);
  __half h; __builtin_memcpy(&h, &bits, 2);
  return __half2float(h);
}

#define P1(acc, pv) { unsigned _p = (pv); acc += __half2float(__ushort_as_half((unsigned short)(_p & 0xFFFFu))) * xc[_p >> 16]; }

__global__ __launch_bounds__(NTHR) void mega(const float* __restrict__ A, float* __restrict__ out) {
  const int c = blockIdx.x;
  const int t = threadIdx.x;
  const int wv = t >> 6, ln = t & 63;

  __shared__ float xv[3][N];
  __shared__ float wl[N];
  __shared__ float degl[N];
  __shared__ double sM1[Q][Q+1];
  __shared__ double sM2[Q][Q+1];
  __shared__ double sM3[Q][Q+1];
  __shared__ double sTheta[Q];
  __shared__ int   sPerm[Q];
  __shared__ float sCoef[CHEB_M*3];
  __shared__ float sRed[16];
  __shared__ int   sKw[16];
  __shared__ double sCs[16][2];
  __shared__ int   sPr[16], sQr[16];
  __shared__ int   sLab[N], sLab2[N];
  __shared__ float sB_, sA_, sLamV, sThQ;
  __shared__ int   sDoneV, sF0, sF1;

  float* xb = &xv[0][0];
  unsigned bcnt = 0;
  int cur = 1;   // after each publish (P = cur?X0:X1; cur^=1), (cur?X1:X0) = last published

  // one-hop symmetric barrier: every block's wave 0 polls all 32 flag lines
  auto GBAR = [&]() {
    __syncthreads();
    ++bcnt;
    if (t < 64) {
      if (ln == 0) {
        __builtin_amdgcn_fence(__ATOMIC_RELEASE, "agent");
        __hip_atomic_store(&g_flags[c*32], bcnt, __ATOMIC_RELAXED, __HIP_MEMORY_SCOPE_AGENT);
      }
      for (;;) {
        unsigned v = bcnt;
        if (ln < NB)
          v = __hip_atomic_load(&g_flags[ln*32], __ATOMIC_RELAXED, __HIP_MEMORY_SCOPE_AGENT);
        if (__all(v >= bcnt)) break;
        __builtin_amdgcn_s_sleep(2);
      }
      if (ln == 0) __builtin_amdgcn_fence(__ATOMIC_ACQUIRE, "agent");
    }
    __syncthreads();
  };

  // coalesced column-major ELL row-dot: thread t owns row t; wave-uniform bound
  auto SPROW = [&](const float* __restrict__ xc) -> float {
    float acc = 0.f, acc2 = 0.f;
    const int kmax = sKw[wv];
    const unsigned* __restrict__ rp = g_rowpT + t;
    for (int k = 0; k < kmax; k += 8) {
      const unsigned* __restrict__ p = rp + k*N;
      unsigned a0 = p[0*N], a1 = p[1*N], a2 = p[2*N], a3 = p[3*N];
      unsigned a4 = p[4*N], a5 = p[5*N], a6 = p[6*N], a7 = p[7*N];
      P1(acc, a0) P1(acc2, a1) P1(acc, a2) P1(acc2, a3)
      P1(acc, a4) P1(acc2, a5) P1(acc, a6) P1(acc2, a7)
    }
    return acc + acc2;
  };

  auto CHSTEP = [&](int cu_, int pv_, int nx, float al, float be, float ga) {
    const float* xc = xb + cu_*N;
    float acc = SPROW(xc);
    float xr = xc[t];
    float o = al*(degl[t]*xr - acc) + be*xr;
    if (ga != 0.f) o += ga * xb[pv_*N + t];
    xb[nx*N + t] = o;
    __syncthreads();
  };

  auto LMUL = [&](int cu_) {
    const float* xc = xb + cu_*N;
    float acc = SPROW(xc);
    wl[t] = degl[t]*xc[t] - acc;
    __syncthreads();
  };

  auto DEFL = [&](int bu) {
    if (c == 0) {
      xb[bu*N + t] = 0.03125f;
    } else {
      float s = xb[bu*N + t];
      for (int o = 32; o; o >>= 1) s += __shfl_xor(s, o);
      if (ln == 0) sRed[wv] = s;
      __syncthreads();
      float tot = 0.f;
      #pragma unroll
      for (int w = 0; w < 16; w++) tot += sRed[w];
      xb[bu*N + t] -= tot / (float)N;
    }
    __syncthreads();
  };

  auto GHROWS = [&](const float* Xp, int cu_) {
    const float* xc = xb + cu_*N;
    for (int k = wv; k < Q; k += 16) {
      const float* mx = Xp + k*N;
      const float* mw = g_W + k*N;
      double pg = 0.0, ph = 0.0;
      for (int s = 0; s < 16; s++) {
        int i = ln + s*64;
        double xv_ = (double)xc[i];
        pg += xv_ * (double)mx[i];
        ph += xv_ * (double)mw[i];
      }
      for (int o = 32; o; o >>= 1) { pg += __shfl_xor(pg, o); ph += __shfl_xor(ph, o); }
      if (ln == 0) { g_G[c*Q + k] = pg; g_H[c*Q + k] = ph; }
    }
  };

  // wave-0-local Cholesky + R^-1 (lockstep; WFENCE = compiler ordering only)
  auto CHOLINV = [&]() {
    for (int id = t; id < Q*Q; id += NTHR) sM1[id>>5][id&31] = g_G[id];
    __syncthreads();
    if (wv == 0) {
      const int j = ln & 31;
      const bool lo = ln < 32;
      double fl;
      { double md = 0.0;
        for (int i = 0; i < Q; i++) md = fmax(md, sM1[i][i]);
        fl = md*1e-13 + 1e-280; }
      for (int k = 0; k < Q; k++) {
        double dkk = sM1[k][k]; if (!(dkk > fl)) dkk = fl;
        double rkk = sqrt(dkk);
        if (lo && j > k) sM1[k][j] /= rkk;
        if (ln == 0) sM1[k][k] = rkk;
        WFENCE();
        if (lo) {
          for (int i = k+1; i < Q; i++)
            if (j >= i) sM1[i][j] -= sM1[k][i]*sM1[k][j];
        }
        WFENCE();
      }
      if (lo) {
        for (int i = 0; i < Q; i++) sM2[i][j] = 0.0;
        sM2[j][j] = 1.0/sM1[j][j];
        for (int i = j-1; i >= 0; i--) {
          double sa = 0.0;
          for (int k2 = i+1; k2 <= j; k2++) sa += sM1[i][k2]*sM2[k2][j];
          sM2[i][j] = -sa/sM1[i][i];
        }
      }
    }
    __syncthreads();
  };

  auto RRTRANS = [&]() {   // sM3 = R^-T * sM3 * R^-1
    int i = t >> 5, j = t & 31;
    double a = 0.0;
    for (int k = 0; k <= i; k++) a += sM2[k][i]*sM3[k][j];
    __syncthreads();
    sM1[i][j] = a;
    __syncthreads();
    double b = 0.0;
    for (int k = 0; k <= j; k++) b += sM1[i][k]*sM2[k][j];
    __syncthreads();
    sM3[i][j] = b;
    __syncthreads();
  };

  auto MULR = [&](const float* Xp, int tb) {   // xb[tb] = Xp * R^-1[:,c]  (orthonormal col)
    float acc = 0.f;
    #pragma unroll
    for (int k = 0; k < Q; k++) acc += Xp[k*N + t] * (float)sM2[k][c];
    xb[tb*N + t] = acc;
    __syncthreads();
  };

  auto POWA = [&]() {
    if (wv == 0) {
      int rl = ln & 31;
      double v = 1.0, w_ = 0.0, nrm = 1.0;
      for (int it = 0; it < 20; it++) {
        w_ = 0.0;
        for (int k2 = 0; k2 < Q; k2++) w_ += sM3[rl][k2]*__shfl(v, k2);
        nrm = 0.0;
        for (int k2 = 0; k2 < Q; k2++) { double wk = __shfl(w_, k2); nrm += wk*wk; }
        nrm = sqrt(nrm) + 1e-300;
        v = w_/nrm;
      }
      if (ln == 0) {
        float b = sB_;
        float a = (float)(nrm*1.1);
        if (a > 0.9f*b) a = 0.9f*b;
        if (a < 0.02f*b) a = 0.02f*b;
        sA_ = a;
      }
    }
    __syncthreads();
  };

  // wave-0-local Jacobi on sM3 (vectors accumulate in sM1)
  auto JACOBI = [&]() {
    for (int id = t; id < Q*Q; id += NTHR) sM1[id>>5][id&31] = ((id>>5) == (id&31)) ? 1.0 : 0.0;
    __syncthreads();
    if (wv == 0) {
      const int cj = ln & 31, half = ln >> 5;
      for (int sw = 0; sw < JSWEEPS; sw++) {
        for (int rr2 = 0; rr2 < 31; rr2++) {
          if (ln < 16) {
            int p, q;
            if (ln == 0) { p = 31; q = rr2 % 31; }
            else { p = (rr2 + ln) % 31; q = (rr2 + 31 - ln) % 31; }
            sPr[ln] = p; sQr[ln] = q;
            double app = sM3[p][p], aqq = sM3[q][q], apq = sM3[p][q];
            double cth, sth;
            if (fabs(apq) < 1e-280) { cth = 1.0; sth = 0.0; }
            else {
              double ta = (aqq - app)/(2.0*apq);
              double tt = (ta >= 0.0 ? 1.0 : -1.0)/(fabs(ta) + sqrt(1.0 + ta*ta));
              cth = 1.0/sqrt(1.0 + tt*tt); sth = tt*cth;
            }
            sCs[ln][0] = cth; sCs[ln][1] = sth;
          }
          WFENCE();
          #pragma unroll
          for (int s = 0; s < 8; s++) {
            int pi = 2*s + half;
            int p = sPr[pi], q = sQr[pi];
            double cth = sCs[pi][0], sth = sCs[pi][1];
            double hp = sM3[p][cj], hq = sM3[q][cj];
            sM3[p][cj] = cth*hp - sth*hq;
            sM3[q][cj] = sth*hp + cth*hq;
          }
          WFENCE();
          #pragma unroll
          for (int s = 0; s < 8; s++) {
            int pi = 2*s + half;
            int p = sPr[pi], q = sQr[pi];
            double cth = sCs[pi][0], sth = sCs[pi][1];
            double hp = sM3[cj][p], hq = sM3[cj][q];
            sM3[cj][p] = cth*hp - sth*hq;
            sM3[cj][q] = sth*hp + cth*hq;
            double vp = sM1[cj][p], vq = sM1[cj][q];
            sM1[cj][p] = cth*vp - sth*vq;
            sM1[cj][q] = sth*vp + cth*vq;
          }
          WFENCE();
        }
      }
      if (ln < Q) sTheta[ln] = sM3[ln][ln];
    }
    __syncthreads();
  };

  auto SORTP = [&]() {
    if (t == 0) {
      double th[Q]; int pm[Q];
      for (int i = 0; i < Q; i++) { th[i] = sTheta[i]; pm[i] = i; }
      for (int i = 1; i < Q; i++) {
        double x = th[i]; int px = pm[i]; int j = i - 1;
        while (j >= 0 && th[j] > x) { th[j+1] = th[j]; pm[j+1] = pm[j]; j--; }
        th[j+1] = x; pm[j+1] = px;
      }
      for (int i = 0; i < Q; i++) { sTheta[i] = th[i]; sPerm[i] = pm[i]; }
      sThQ = (float)th[Q-1];                 // largest tracked Ritz value
    }
    __syncthreads();
  };

  auto EIG = [&](int nrounds, bool warm) {
    degl[t] = g_deg[t];
    __syncthreads();
    float mx = degl[t];
    for (int o = 32; o; o >>= 1) mx = fmaxf(mx, __shfl_xor(mx, o));
    if (ln == 0) sRed[wv] = mx;
    __syncthreads();
    if (t == 0) {
      float mm = 0.f;
      for (int w = 0; w < 16; w++) mm = fmaxf(mm, sRed[w]);
      float b = fmaxf(2.02f*mm, 1e-3f) + 1e-6f;
      float aa = 0.5f*b;
      if (warm) {
        // tighten the suppression window just above the tracked subspace
        float ta = 1.15f*sThQ;
        if (ta > 0.5f*b)  ta = 0.5f*b;
        if (ta < 0.02f*b) ta = 0.02f*b;
        aa = ta;
      }
      sB_ = b; sA_ = aa;
    }
    __syncthreads();
    {
      float v;
      if (c == 0) v = 0.03125f;
      else if (warm) v = (cur ? g_X1 : g_X0)[c*N + t];  // last published = ORTHONORMAL Y (own column)
      else {
        unsigned h = (unsigned)t*1664525u + (unsigned)c*1013904223u + 12345u;
        h ^= h >> 16; h *= 2246822519u; h ^= h >> 13; h *= 3266489917u; h ^= h >> 16;
        v = ((float)(h & 0xFFFFFFu)/16777216.f) - 0.5f;
      }
      xb[t] = v;
    }
    __syncthreads();
    DEFL(0);
    int cu = 0;
    for (int round = 0; round < nrounds; round++) {
      if (t == 0) {
        double b = sB_, a = sA_;
        double e = 0.5*(b - a), cc = 0.5*(b + a);
        double s1 = e/(0.0 - cc);
        sCoef[0] = (float)(s1/e); sCoef[1] = (float)(-cc*(s1/e)); sCoef[2] = 0.f;
        double sp = s1;
        for (int k = 1; k < CHEB_M; k++) {
          double snn = 1.0/(2.0/s1 - sp);
          double a2 = 2.0*snn/e;
          sCoef[k*3] = (float)a2; sCoef[k*3+1] = (float)(-cc*a2); sCoef[k*3+2] = (float)(-sp*snn);
          sp = snn;
        }
      }
      __syncthreads();
      int pv_ = (cu+1)%3, nx = (cu+2)%3;
      for (int k = 0; k < CHEB_M; k++) {
        CHSTEP(cu, pv_, nx, sCoef[k*3], sCoef[k*3+1], sCoef[k*3+2]);
        int op = pv_; pv_ = cu; cu = nx; nx = op;
        if (k == 4 || k == 9 || k == CHEB_M-1) { DEFL(cu); DEFL(pv_); }
      }
      LMUL(cu);
      float* Xp = (cur ? g_X0 : g_X1);   // publish raw filtered basis
      cur ^= 1;
      Xp[c*N + t] = xb[cu*N + t];
      g_W[c*N + t] = wl[t];
      GBAR();                                      // X,W published
      GHROWS(Xp, cu);
      GBAR();                                      // G,Htilde complete
      for (int id = t; id < Q*Q; id += NTHR) sM3[id>>5][id&31] = g_H[id];
      CHOLINV();
      RRTRANS();
      if (round < nrounds-1) {
        POWA();
        MULR(Xp, 0); cu = 0;
      } else {
        JACOBI();
        SORTP();
        MULR(Xp, 0);                               // xb0 = own ORTHONORMAL column Y_c
        float* Yp = (cur ? g_X0 : g_X1);           // publish Y for future warm starts
        cur ^= 1;
        Yp[c*N + t] = xb[t];
        GBAR();                                    // Y published
        if (c < 8) {                               // F = Y * V[:,perm(c)]
          int pc = sPerm[c];
          float acc = 0.f;
          #pragma unroll
          for (int k = 0; k < Q; k++) acc += Yp[k*N + t] * (float)sM1[k][pc];
          g_Fc[t*8 + c] = acc;
        }
        GBAR();                                    // F published
      }
    }
  };

  // ================= BUILD =================
  for (int s2 = 0; s2 < 2; s2++) {
    int r = c*32 + wv*2 + s2;
    int cnt = 0;
    for (int c0 = 0; c0 < N; c0 += 64) {
      int j = c0 + ln;
      float v = A[r*N + j];
      bool keep = (j != r) && (v > 0.f);
      unsigned long long m = __ballot(keep);
      int pos = __popcll(m & ((1ull << ln) - 1ull));
      if (keep) {
        int w = cnt + pos;
        if (w < W1) { g_idx1[r*W1 + w] = (unsigned short)j; g_a0[r*W1 + w] = v; }
        g_Sd[j*N + r] = v;
      }
      cnt += __popcll(m);
    }
    cnt = cnt < W1 ? cnt : W1;
    if (ln == 0) g_nnz1[r] = cnt;
    g_u[r*W1 + ln] = 1.f;
    g_s[r*W1 + ln] = 0.f;
  }
  GBAR();
  for (int s2 = 0; s2 < 2; s2++) {
    int r = c*32 + wv*2 + s2;
    int cnt = 0; float dacc = 0.f;
    for (int c0 = 0; c0 < N; c0 += 64) {
      int j = c0 + ln;
      float vr = A[r*N + j];
      float vc = g_Sd[r*N + j];
      bool keep = (j != r) && (vr > 0.f || vc > 0.f);
      unsigned long long m = __ballot(keep);
      int pos = __popcll(m & ((1ull << ln) - 1ull));
      if (keep) {
        int w = cnt + pos;
        if (w < W2S) {
          float val = 0.5f*(vr + vc);
          unsigned pv = packrw((unsigned)j, val);
          g_rowpT[w*N + r] = pv;
          g_jidx[r*W2S + w] = (unsigned short)j;
          g_w2[r*W2S + w] = val;
          g_w2fin[r*W2S + w] = val;
          dacc += unpackw(pv);
        }
      }
      cnt += __popcll(m);
    }
    for (int o = 32; o; o >>= 1) dacc += __shfl_xor(dacc, o);
    cnt = cnt < W2S ? cnt : W2S;
    int nz8 = (cnt + 7) & ~7; if (nz8 < 8) nz8 = 8;
    if (ln == 0) { g_nnz2[r] = cnt; g_nz8[r] = nz8; g_deg[r] = dacc; }
    for (int w = cnt + ln; w < W2S; w += 64) {
      g_rowpT[w*N + r] = ((unsigned)r) << 16;    // zero-weight padding
      g_w2[r*W2S + w] = 0.f;
      g_w2fin[r*W2S + w] = 0.f;
    }
    for (int j = ln; j < N; j += 64) g_Sd[r*N + j] = 0.f;
  }
  GBAR();

  // per-wave static padded-nnz bound (thread t owns row t in the chain)
  {
    int m = g_nz8[t];
    for (int o = 32; o; o >>= 1) { int v = __shfl_xor(m, o); m = v > m ? v : m; }
    if (ln == 0) sKw[wv] = m;
    if (t == 0) { sLamV = 0.01f; sDoneV = 0; sThQ = 0.f; }
    __syncthreads();
  }

  // ================= initial (cold) eigensolve -> F, sn =================
  EIG(ROUNDS_COLD, false);
  if (t < 256) g_F[c*256 + t] = g_Fc[c*256 + t];
  __syncthreads();
  if (t < 32) {
    int r = c*32 + t; float ss = 0.f;
    #pragma unroll
    for (int d = 0; d < 8; d++) { float v = g_F[r*8 + d]; ss += v*v; }
    g_sn[r] = ss;
  }
  GBAR();

  // ================= CLR iterations =================
  for (int iter = 0; iter < NITER; iter++) {
    {
      float lamreg = sLamV;
      for (int s2 = 0; s2 < 2; s2++) {
        int r = c*32 + wv*2 + s2;
        int nnz = g_nnz1[r];
        bool valid = ln < nnz;
        int e = r*W1 + ln;
        int cidx = valid ? (int)g_idx1[e] : 0;
        float a0v = valid ? g_a0[e] : 0.f;
        float uu = valid ? g_u[e] : 1.f;
        float fr[8];
        #pragma unroll
        for (int d = 0; d < 8; d++) fr[d] = g_F[r*8 + d];
        float dot = 0.f;
        #pragma unroll
        for (int d = 0; d < 8; d++) dot += fr[d]*g_F[cidx*8 + d];
        float dist = fmaxf(g_sn[r] + g_sn[cidx] - 2.f*dot, 0.f);
        float dd = uu*a0v - 0.5f*lamreg*dist;
        float tmin = valid ? (uu - dd) : 3.0e38f;
        for (int o = 32; o; o >>= 1) tmin = fminf(tmin, __shfl_xor(tmin, o));
        float lam = (tmin < 3.0e38f) ? tmin : 0.f;
        for (int it = 0; it < NEWT; it++) {
          float v1 = (lam + dd)/uu;
          bool pos = valid && (v1 > 0.f);
          float gg = pos ? (1.f/uu) : 0.f;
          float ff = pos ? v1 : 0.f;
          for (int o = 32; o; o >>= 1) { gg += __shfl_xor(gg, o); ff += __shfl_xor(ff, o); }
          float f = ff - 1.f;
          float step = f/(gg > 0.f ? gg : 1.f);
          lam = (fabsf(f) > 1e-8f) ? (lam - step) : lam;
        }
        float v1 = (lam + dd)/uu;
        float sv = fmaxf(v1, 0.f);
        if (valid) {
          g_snew[e] = sv;
          float df = sv - a0v;
          g_unew[e] = 1.f/(2.f*sqrtf(df*df + 2.2204e-16f));
          g_Sd[r*N + cidx] = sv;
        }
      }
    }
    GBAR();
    for (int s2 = 0; s2 < 2; s2++) {
      int r = c*32 + wv*2 + s2;
      int nnz = g_nnz2[r];
      float dacc = 0.f;
      for (int k2 = ln; k2 < nnz; k2 += 64) {
        int j = (int)g_jidx[r*W2S + k2];
        float v = 0.5f*(g_Sd[r*N + j] + g_Sd[j*N + r]);
        unsigned np = packrw((unsigned)j, v);
        g_w2[r*W2S + k2] = v;
        g_rowpT[k2*N + r] = np;
        dacc += unpackw(np);
      }
      for (int o = 32; o; o >>= 1) dacc += __shfl_xor(dacc, o);
      if (ln == 0) g_deg[r] = dacc;
    }
    GBAR();
    if (iter < NITER-1) {
      // first in-loop solve spans the A->S operator change: full cold solve.
      // later solves see small incremental changes: warm 1-round solve from
      // orthonormal Y with theta-tightened filter window.
      if (iter == 0) EIG(ROUNDS_COLD, false);
      else           EIG(ROUNDS_WARM, true);
      if (t == 0) {
        double fn1 = 0.0;
        for (int i = 0; i < 8; i++) fn1 += sTheta[i];
        double fn2 = fn1 + sTheta[8];
        int done = sDoneV; float lam = sLamV;
        int c1 = (fn1 > 1e-10) ? 1 : 0;
        int c2 = ((!c1) && (fn2 < 1e-10)) ? 1 : 0;
        sF0 = !done;
        sF1 = (!done) && (!c2);
        if (!done) { if (c1) lam *= 2.f; else if (c2) lam *= 0.5f; sLamV = lam; }
        sDoneV = done || ((!c1) && (!c2));
      }
    } else {
      if (t == 0) { sF0 = !sDoneV; sF1 = 0; }
    }
    __syncthreads();
    if (sF0) {
      for (int k2 = t; k2 < 32*W1; k2 += NTHR) { int id = c*32*W1 + k2; g_s[id] = g_snew[id]; g_u[id] = g_unew[id]; }
      for (int k2 = t; k2 < 32*W2S; k2 += NTHR) { int id = c*32*W2S + k2; g_w2fin[id] = g_w2[id]; }
    }
    if (sF1) {
      if (t < 256) g_F[c*256 + t] = g_Fc[c*256 + t];
    }
    __syncthreads();
    if (t < 32) {                              // sn from (possibly updated) F
      int r = c*32 + t; float ss = 0.f;
      #pragma unroll
      for (int d = 0; d < 8; d++) { float v = g_F[r*8 + d]; ss += v*v; }
      g_sn[r] = ss;
    }
    GBAR();
  }

  // ================= outputs: S =================
  for (int s2 = 0; s2 < 2; s2++) {
    int r = c*32 + wv*2 + s2;
    if (ln < g_nnz1[r]) out[N + r*N + (int)g_idx1[r*W1 + ln]] = g_s[r*W1 + ln];
  }

  // ================= connected components (block 0) =================
  if (c == 0) {
    sLab[t] = t;
    __syncthreads();
    for (int it2 = 0; it2 < CCIT; it2++) {
      int nnz = g_nnz2[t];
      int m = sLab[t];
      for (int k2 = 0; k2 < nnz; k2++) {
        if (g_w2fin[t*W2S + k2] > 0.f) {
          int l2 = sLab[(int)g_jidx[t*W2S + k2]];
          m = m < l2 ? m : l2;
        }
      }
      sLab2[t] = m;
      __syncthreads();
      sLab[t] = sLab2[sLab2[t]];
      __syncthreads();
    }
    out[t] = (float)sLab[t];
  }
}

extern "C" void kernel_launch(void* const* d_in, const int* in_sizes, int n_in,
                              void* d_out, int out_size, void* d_ws, size_t ws_size,
                              hipStream_t stream) {
  const float* A = (const float*)d_in[0];
  float* out = (float*)d_out;

  void *pSd, *pFlags;
  hipGetSymbolAddress(&pSd,    HIP_SYMBOL(g_Sd));
  hipGetSymbolAddress(&pFlags, HIP_SYMBOL(g_flags));

  hipMemsetAsync(pSd, 0, sizeof(float)*(size_t)N*N, stream);
  hipMemsetAsync(pFlags, 0, sizeof(unsigned)*NB*32, stream);
  hipMemsetAsync(d_out, 0, sizeof(float)*(size_t)out_size, stream);

  mega<<<NB, NTHR, 0, stream>>>(A, out);
}

// Round 12
// 4032.598 us; speedup vs baseline: 1.8747x; 1.1096x over previous
//
#include <hip/hip_runtime.h>
#include <hip/hip_fp16.h>
#include <math.h>

#define N 1024
#define W1 64
#define W2S 96
#define Q 32
#define NB 32
#define NTHR 1024
#define CHEB_M 16
#define CHEB_WARM 12
#define ROUNDS_COLD0 2
#define ROUNDS_COLD 3
#define ROUNDS_WARM 1
#define NITER 6
#define NEWT 20
#define JSWEEPS 5
#define CCIT 8

#define WFENCE() asm volatile("" ::: "memory")

// ---------------- device state ----------------
__device__ unsigned g_flags[NB*32];
__device__ unsigned short g_idx1[N*W1];
__device__ float g_a0[N*W1], g_u[N*W1], g_unew[N*W1], g_s[N*W1], g_snew[N*W1];
__device__ int g_nnz1[N], g_nnz2[N], g_nz8[N];
__device__ unsigned g_rowpT[W2S*N];            // COLUMN-major packed: (idx<<16)|f16(w)
__device__ unsigned short g_jidx[N*W2S];       // row-major idx list
__device__ float g_w2[N*W2S], g_w2fin[N*W2S];
__device__ float g_deg[N], g_sn[N];
__device__ float g_Sd[N*N];
__device__ float g_X0[Q*N], g_X1[Q*N], g_W[Q*N];
__device__ double g_G[Q*Q], g_H[Q*Q];
__device__ float g_F[N*8], g_Fc[N*8];

__device__ __forceinline__ unsigned packrw(unsigned j, float w) {
  __half h = __float2half_rn(w);
  unsigned short bits; __builtin_memcpy(&bits, &h, 2);
  return (j << 16) | (unsigned)bits;
}
__device__ __forceinline__ float unpackw(unsigned v) {
  unsigned short bits = (unsigned short)(v & 0xFFFFu);
  __half h; __builtin_memcpy(&h, &bits, 2);
  return __half2float(h);
}

#define P1(acc, pv) { unsigned _p = (pv); acc += __half2float(__ushort_as_half((unsigned short)(_p & 0xFFFFu))) * xc[_p >> 16]; }

__global__ __launch_bounds__(NTHR) void mega(const float* __restrict__ A, float* __restrict__ out) {
  const int c = blockIdx.x;
  const int t = threadIdx.x;
  const int wv = t >> 6, ln = t & 63;

  __shared__ float xv[3][N];
  __shared__ float wl[N];
  __shared__ float degl[N];
  __shared__ double sM1[Q][Q+1];
  __shared__ double sM2[Q][Q+1];
  __shared__ double sM3[Q][Q+1];
  __shared__ float sFQ[Q][8];
  __shared__ double sTheta[Q];
  __shared__ int   sPerm[Q];
  __shared__ float sCoef[CHEB_M*3];
  __shared__ float sRed[16];
  __shared__ int   sKw[16];
  __shared__ double sCs[16][2];
  __shared__ int   sPr[16], sQr[16];
  __shared__ int   sLab[N], sLab2[N];
  __shared__ float sB_, sA_, sLamV, sThQ;
  __shared__ int   sDoneV, sF0, sF1;

  float* xb = &xv[0][0];
  unsigned bcnt = 0;
  int cur = 1;   // after each publish (P = cur?X0:X1; cur^=1), (cur?X1:X0) = last published

  // one-hop symmetric barrier: every block's wave 0 polls all 32 flag lines
  auto GBAR = [&]() {
    __syncthreads();
    ++bcnt;
    if (t < 64) {
      if (ln == 0) {
        __builtin_amdgcn_fence(__ATOMIC_RELEASE, "agent");
        __hip_atomic_store(&g_flags[c*32], bcnt, __ATOMIC_RELAXED, __HIP_MEMORY_SCOPE_AGENT);
      }
      for (;;) {
        unsigned v = bcnt;
        if (ln < NB)
          v = __hip_atomic_load(&g_flags[ln*32], __ATOMIC_RELAXED, __HIP_MEMORY_SCOPE_AGENT);
        if (__all(v >= bcnt)) break;
        __builtin_amdgcn_s_sleep(2);
      }
      if (ln == 0) __builtin_amdgcn_fence(__ATOMIC_ACQUIRE, "agent");
    }
    __syncthreads();
  };

  // coalesced column-major ELL row-dot: thread t owns row t; wave-uniform bound
  auto SPROW = [&](const float* __restrict__ xc) -> float {
    float acc = 0.f, acc2 = 0.f;
    const int kmax = sKw[wv];
    const unsigned* __restrict__ rp = g_rowpT + t;
    for (int k = 0; k < kmax; k += 8) {
      const unsigned* __restrict__ p = rp + k*N;
      unsigned a0 = p[0*N], a1 = p[1*N], a2 = p[2*N], a3 = p[3*N];
      unsigned a4 = p[4*N], a5 = p[5*N], a6 = p[6*N], a7 = p[7*N];
      P1(acc, a0) P1(acc2, a1) P1(acc, a2) P1(acc2, a3)
      P1(acc, a4) P1(acc2, a5) P1(acc, a6) P1(acc2, a7)
    }
    return acc + acc2;
  };

  auto CHSTEP = [&](int cu_, int pv_, int nx, float al, float be, float ga) {
    const float* xc = xb + cu_*N;
    float acc = SPROW(xc);
    float xr = xc[t];
    float o = al*(degl[t]*xr - acc) + be*xr;
    if (ga != 0.f) o += ga * xb[pv_*N + t];
    xb[nx*N + t] = o;
    __syncthreads();
  };

  auto LMUL = [&](int cu_) {
    const float* xc = xb + cu_*N;
    float acc = SPROW(xc);
    wl[t] = degl[t]*xc[t] - acc;
    __syncthreads();
  };

  auto DEFL = [&](int bu) {
    if (c == 0) {
      xb[bu*N + t] = 0.03125f;
    } else {
      float s = xb[bu*N + t];
      for (int o = 32; o; o >>= 1) s += __shfl_xor(s, o);
      if (ln == 0) sRed[wv] = s;
      __syncthreads();
      float tot = 0.f;
      #pragma unroll
      for (int w = 0; w < 16; w++) tot += sRed[w];
      xb[bu*N + t] -= tot / (float)N;
    }
    __syncthreads();
  };

  auto GHROWS = [&](const float* Xp, int cu_) {
    const float* xc = xb + cu_*N;
    for (int k = wv; k < Q; k += 16) {
      const float* mx = Xp + k*N;
      const float* mw = g_W + k*N;
      double pg = 0.0, ph = 0.0;
      for (int s = 0; s < 16; s++) {
        int i = ln + s*64;
        double xv_ = (double)xc[i];
        pg += xv_ * (double)mx[i];
        ph += xv_ * (double)mw[i];
      }
      for (int o = 32; o; o >>= 1) { pg += __shfl_xor(pg, o); ph += __shfl_xor(ph, o); }
      if (ln == 0) { g_G[c*Q + k] = pg; g_H[c*Q + k] = ph; }
    }
  };

  // wave-0-local Cholesky + R^-1 (lockstep; WFENCE = compiler ordering only)
  auto CHOLINV = [&]() {
    for (int id = t; id < Q*Q; id += NTHR) sM1[id>>5][id&31] = g_G[id];
    __syncthreads();
    if (wv == 0) {
      const int j = ln & 31;
      const bool lo = ln < 32;
      double fl;
      { double md = 0.0;
        for (int i = 0; i < Q; i++) md = fmax(md, sM1[i][i]);
        fl = md*1e-13 + 1e-280; }
      for (int k = 0; k < Q; k++) {
        double dkk = sM1[k][k]; if (!(dkk > fl)) dkk = fl;
        double rkk = sqrt(dkk);
        if (lo && j > k) sM1[k][j] /= rkk;
        if (ln == 0) sM1[k][k] = rkk;
        WFENCE();
        if (lo) {
          for (int i = k+1; i < Q; i++)
            if (j >= i) sM1[i][j] -= sM1[k][i]*sM1[k][j];
        }
        WFENCE();
      }
      if (lo) {
        for (int i = 0; i < Q; i++) sM2[i][j] = 0.0;
        sM2[j][j] = 1.0/sM1[j][j];
        for (int i = j-1; i >= 0; i--) {
          double sa = 0.0;
          for (int k2 = i+1; k2 <= j; k2++) sa += sM1[i][k2]*sM2[k2][j];
          sM2[i][j] = -sa/sM1[i][i];
        }
      }
    }
    __syncthreads();
  };

  auto RRTRANS = [&]() {   // sM3 = R^-T * sM3 * R^-1
    int i = t >> 5, j = t & 31;
    double a = 0.0;
    for (int k = 0; k <= i; k++) a += sM2[k][i]*sM3[k][j];
    __syncthreads();
    sM1[i][j] = a;
    __syncthreads();
    double b = 0.0;
    for (int k = 0; k <= j; k++) b += sM1[i][k]*sM2[k][j];
    __syncthreads();
    sM3[i][j] = b;
    __syncthreads();
  };

  auto MULR = [&](const float* Xp, int tb) {   // xb[tb] = Xp * R^-1[:,c]  (orthonormal col)
    float acc = 0.f;
    #pragma unroll
    for (int k = 0; k < Q; k++) acc += Xp[k*N + t] * (float)sM2[k][c];
    xb[tb*N + t] = acc;
    __syncthreads();
  };

  auto POWA = [&]() {
    if (wv == 0) {
      int rl = ln & 31;
      double v = 1.0, w_ = 0.0, nrm = 1.0;
      for (int it = 0; it < 20; it++) {
        w_ = 0.0;
        for (int k2 = 0; k2 < Q; k2++) w_ += sM3[rl][k2]*__shfl(v, k2);
        nrm = 0.0;
        for (int k2 = 0; k2 < Q; k2++) { double wk = __shfl(w_, k2); nrm += wk*wk; }
        nrm = sqrt(nrm) + 1e-300;
        v = w_/nrm;
      }
      if (ln == 0) {
        float b = sB_;
        float a = (float)(nrm*1.1);
        if (a > 0.9f*b) a = 0.9f*b;
        if (a < 0.02f*b) a = 0.02f*b;
        sA_ = a;
      }
    }
    __syncthreads();
  };

  // wave-0-local Jacobi on sM3 (vectors accumulate in sM1)
  auto JACOBI = [&]() {
    for (int id = t; id < Q*Q; id += NTHR) sM1[id>>5][id&31] = ((id>>5) == (id&31)) ? 1.0 : 0.0;
    __syncthreads();
    if (wv == 0) {
      const int cj = ln & 31, half = ln >> 5;
      for (int sw = 0; sw < JSWEEPS; sw++) {
        for (int rr2 = 0; rr2 < 31; rr2++) {
          if (ln < 16) {
            int p, q;
            if (ln == 0) { p = 31; q = rr2 % 31; }
            else { p = (rr2 + ln) % 31; q = (rr2 + 31 - ln) % 31; }
            sPr[ln] = p; sQr[ln] = q;
            double app = sM3[p][p], aqq = sM3[q][q], apq = sM3[p][q];
            double cth, sth;
            if (fabs(apq) < 1e-280) { cth = 1.0; sth = 0.0; }
            else {
              double ta = (aqq - app)/(2.0*apq);
              double tt = (ta >= 0.0 ? 1.0 : -1.0)/(fabs(ta) + sqrt(1.0 + ta*ta));
              cth = 1.0/sqrt(1.0 + tt*tt); sth = tt*cth;
            }
            sCs[ln][0] = cth; sCs[ln][1] = sth;
          }
          WFENCE();
          #pragma unroll
          for (int s = 0; s < 8; s++) {
            int pi = 2*s + half;
            int p = sPr[pi], q = sQr[pi];
            double cth = sCs[pi][0], sth = sCs[pi][1];
            double hp = sM3[p][cj], hq = sM3[q][cj];
            sM3[p][cj] = cth*hp - sth*hq;
            sM3[q][cj] = sth*hp + cth*hq;
          }
          WFENCE();
          #pragma unroll
          for (int s = 0; s < 8; s++) {
            int pi = 2*s + half;
            int p = sPr[pi], q = sQr[pi];
            double cth = sCs[pi][0], sth = sCs[pi][1];
            double hp = sM3[cj][p], hq = sM3[cj][q];
            sM3[cj][p] = cth*hp - sth*hq;
            sM3[cj][q] = sth*hp + cth*hq;
            double vp = sM1[cj][p], vq = sM1[cj][q];
            sM1[cj][p] = cth*vp - sth*vq;
            sM1[cj][q] = sth*vp + cth*vq;
          }
          WFENCE();
        }
      }
      if (ln < Q) sTheta[ln] = sM3[ln][ln];
    }
    __syncthreads();
  };

  auto SORTP = [&]() {
    if (t == 0) {
      double th[Q]; int pm[Q];
      for (int i = 0; i < Q; i++) { th[i] = sTheta[i]; pm[i] = i; }
      for (int i = 1; i < Q; i++) {
        double x = th[i]; int px = pm[i]; int j = i - 1;
        while (j >= 0 && th[j] > x) { th[j+1] = th[j]; pm[j+1] = pm[j]; j--; }
        th[j+1] = x; pm[j+1] = px;
      }
      for (int i = 0; i < Q; i++) { sTheta[i] = th[i]; sPerm[i] = pm[i]; }
      sThQ = (float)th[Q-1];                 // largest tracked Ritz value
    }
    __syncthreads();
  };

  auto EIG = [&](int nrounds, bool warm, int cm) {
    degl[t] = g_deg[t];
    __syncthreads();
    float mx = degl[t];
    for (int o = 32; o; o >>= 1) mx = fmaxf(mx, __shfl_xor(mx, o));
    if (ln == 0) sRed[wv] = mx;
    __syncthreads();
    if (t == 0) {
      float mm = 0.f;
      for (int w = 0; w < 16; w++) mm = fmaxf(mm, sRed[w]);
      float b = fmaxf(2.02f*mm, 1e-3f) + 1e-6f;
      float aa = 0.5f*b;
      if (warm) {
        // tighten the suppression window just above the tracked subspace
        float ta = 1.15f*sThQ;
        if (ta > 0.5f*b)  ta = 0.5f*b;
        if (ta < 0.02f*b) ta = 0.02f*b;
        aa = ta;
      }
      sB_ = b; sA_ = aa;
    }
    __syncthreads();
    {
      float v;
      if (c == 0) v = 0.03125f;
      else if (warm) v = (cur ? g_X1 : g_X0)[c*N + t];  // last published = ORTHONORMAL Y (own column)
      else {
        unsigned h = (unsigned)t*1664525u + (unsigned)c*1013904223u + 12345u;
        h ^= h >> 16; h *= 2246822519u; h ^= h >> 13; h *= 3266489917u; h ^= h >> 16;
        v = ((float)(h & 0xFFFFFFu)/16777216.f) - 0.5f;
      }
      xb[t] = v;
    }
    __syncthreads();
    DEFL(0);
    int cu = 0;
    for (int round = 0; round < nrounds; round++) {
      if (t == 0) {
        double b = sB_, a = sA_;
        double e = 0.5*(b - a), cc = 0.5*(b + a);
        double s1 = e/(0.0 - cc);
        sCoef[0] = (float)(s1/e); sCoef[1] = (float)(-cc*(s1/e)); sCoef[2] = 0.f;
        double sp = s1;
        for (int k = 1; k < cm; k++) {
          double snn = 1.0/(2.0/s1 - sp);
          double a2 = 2.0*snn/e;
          sCoef[k*3] = (float)a2; sCoef[k*3+1] = (float)(-cc*a2); sCoef[k*3+2] = (float)(-sp*snn);
          sp = snn;
        }
      }
      __syncthreads();
      int pv_ = (cu+1)%3, nx = (cu+2)%3;
      for (int k = 0; k < cm; k++) {
        CHSTEP(cu, pv_, nx, sCoef[k*3], sCoef[k*3+1], sCoef[k*3+2]);
        int op = pv_; pv_ = cu; cu = nx; nx = op;
        if (k == 4 || k == 9 || k == cm-1) { DEFL(cu); DEFL(pv_); }
      }
      LMUL(cu);
      float* Xp = (cur ? g_X0 : g_X1);   // publish raw filtered basis
      cur ^= 1;
      Xp[c*N + t] = xb[cu*N + t];
      g_W[c*N + t] = wl[t];
      GBAR();                                      // X,W published
      GHROWS(Xp, cu);
      GBAR();                                      // G,Htilde complete
      for (int id = t; id < Q*Q; id += NTHR) sM3[id>>5][id&31] = g_H[id];
      CHOLINV();
      RRTRANS();
      if (round < nrounds-1) {
        POWA();
        MULR(Xp, 0); cu = 0;
      } else {
        JACOBI();
        SORTP();
        if (t < 256) {                             // FQ = R^-1 * V[:,perm(0..7)] (block-local f64)
          int k = t >> 3, cc2 = t & 7;
          int pc = sPerm[cc2];
          double a = 0.0;
          for (int m = 0; m < Q; m++) a += sM2[k][m]*sM1[m][pc];
          sFQ[k][cc2] = (float)a;
        }
        MULR(Xp, 0);                               // xb0 = own ORTHONORMAL column Y_c (syncs sFQ too)
        float* Yp = (cur ? g_X0 : g_X1);           // publish Y for future warm starts
        cur ^= 1;
        Yp[c*N + t] = xb[t];
        if (c < 8) {                               // F = X * FQ[:,c]  (X already published)
          float acc = 0.f;
          #pragma unroll
          for (int k = 0; k < Q; k++) acc += Xp[k*N + t] * sFQ[k][c];
          g_Fc[t*8 + c] = acc;
        }
        GBAR();                                    // Y + F published (merged barrier)
      }
    }
  };

  // ================= BUILD =================
  for (int s2 = 0; s2 < 2; s2++) {
    int r = c*32 + wv*2 + s2;
    int cnt = 0;
    for (int c0 = 0; c0 < N; c0 += 64) {
      int j = c0 + ln;
      float v = A[r*N + j];
      bool keep = (j != r) && (v > 0.f);
      unsigned long long m = __ballot(keep);
      int pos = __popcll(m & ((1ull << ln) - 1ull));
      if (keep) {
        int w = cnt + pos;
        if (w < W1) { g_idx1[r*W1 + w] = (unsigned short)j; g_a0[r*W1 + w] = v; }
        g_Sd[j*N + r] = v;
      }
      cnt += __popcll(m);
    }
    cnt = cnt < W1 ? cnt : W1;
    if (ln == 0) g_nnz1[r] = cnt;
    g_u[r*W1 + ln] = 1.f;
    g_s[r*W1 + ln] = 0.f;
  }
  GBAR();
  for (int s2 = 0; s2 < 2; s2++) {
    int r = c*32 + wv*2 + s2;
    int cnt = 0; float dacc = 0.f;
    for (int c0 = 0; c0 < N; c0 += 64) {
      int j = c0 + ln;
      float vr = A[r*N + j];
      float vc = g_Sd[r*N + j];
      bool keep = (j != r) && (vr > 0.f || vc > 0.f);
      unsigned long long m = __ballot(keep);
      int pos = __popcll(m & ((1ull << ln) - 1ull));
      if (keep) {
        int w = cnt + pos;
        if (w < W2S) {
          float val = 0.5f*(vr + vc);
          unsigned pv = packrw((unsigned)j, val);
          g_rowpT[w*N + r] = pv;
          g_jidx[r*W2S + w] = (unsigned short)j;
          g_w2[r*W2S + w] = val;
          g_w2fin[r*W2S + w] = val;
          dacc += unpackw(pv);
        }
      }
      cnt += __popcll(m);
    }
    for (int o = 32; o; o >>= 1) dacc += __shfl_xor(dacc, o);
    cnt = cnt < W2S ? cnt : W2S;
    int nz8 = (cnt + 7) & ~7; if (nz8 < 8) nz8 = 8;
    if (ln == 0) { g_nnz2[r] = cnt; g_nz8[r] = nz8; g_deg[r] = dacc; }
    for (int w = cnt + ln; w < W2S; w += 64) {
      g_rowpT[w*N + r] = ((unsigned)r) << 16;    // zero-weight padding
      g_w2[r*W2S + w] = 0.f;
      g_w2fin[r*W2S + w] = 0.f;
    }
    for (int j = ln; j < N; j += 64) g_Sd[r*N + j] = 0.f;
  }
  GBAR();

  // per-wave static padded-nnz bound (thread t owns row t in the chain)
  {
    int m = g_nz8[t];
    for (int o = 32; o; o >>= 1) { int v = __shfl_xor(m, o); m = v > m ? v : m; }
    if (ln == 0) sKw[wv] = m;
    if (t == 0) { sLamV = 0.01f; sDoneV = 0; sThQ = 0.f; }
    __syncthreads();
  }

  // ================= initial (cold) eigensolve -> F, sn =================
  EIG(ROUNDS_COLD0, false, CHEB_M);
  if (t < 256) g_F[c*256 + t] = g_Fc[c*256 + t];
  __syncthreads();
  if (t < 32) {
    int r = c*32 + t; float ss = 0.f;
    #pragma unroll
    for (int d = 0; d < 8; d++) { float v = g_F[r*8 + d]; ss += v*v; }
    g_sn[r] = ss;
  }
  GBAR();

  // ================= CLR iterations =================
  for (int iter = 0; iter < NITER; iter++) {
    {
      float lamreg = sLamV;
      for (int s2 = 0; s2 < 2; s2++) {
        int r = c*32 + wv*2 + s2;
        int nnz = g_nnz1[r];
        bool valid = ln < nnz;
        int e = r*W1 + ln;
        int cidx = valid ? (int)g_idx1[e] : 0;
        float a0v = valid ? g_a0[e] : 0.f;
        float uu = valid ? g_u[e] : 1.f;
        float fr[8];
        #pragma unroll
        for (int d = 0; d < 8; d++) fr[d] = g_F[r*8 + d];
        float dot = 0.f;
        #pragma unroll
        for (int d = 0; d < 8; d++) dot += fr[d]*g_F[cidx*8 + d];
        float dist = fmaxf(g_sn[r] + g_sn[cidx] - 2.f*dot, 0.f);
        float dd = uu*a0v - 0.5f*lamreg*dist;
        float tmin = valid ? (uu - dd) : 3.0e38f;
        for (int o = 32; o; o >>= 1) tmin = fminf(tmin, __shfl_xor(tmin, o));
        float lam = (tmin < 3.0e38f) ? tmin : 0.f;
        for (int it = 0; it < NEWT; it++) {
          float v1 = (lam + dd)/uu;
          bool pos = valid && (v1 > 0.f);
          float gg = pos ? (1.f/uu) : 0.f;
          float ff = pos ? v1 : 0.f;
          for (int o = 32; o; o >>= 1) { gg += __shfl_xor(gg, o); ff += __shfl_xor(ff, o); }
          float f = ff - 1.f;
          float step = f/(gg > 0.f ? gg : 1.f);
          lam = (fabsf(f) > 1e-8f) ? (lam - step) : lam;
        }
        float v1 = (lam + dd)/uu;
        float sv = fmaxf(v1, 0.f);
        if (valid) {
          g_snew[e] = sv;
          float df = sv - a0v;
          g_unew[e] = 1.f/(2.f*sqrtf(df*df + 2.2204e-16f));
          g_Sd[r*N + cidx] = sv;
        }
      }
    }
    GBAR();
    for (int s2 = 0; s2 < 2; s2++) {
      int r = c*32 + wv*2 + s2;
      int nnz = g_nnz2[r];
      float dacc = 0.f;
      for (int k2 = ln; k2 < nnz; k2 += 64) {
        int j = (int)g_jidx[r*W2S + k2];
        float v = 0.5f*(g_Sd[r*N + j] + g_Sd[j*N + r]);
        unsigned np = packrw((unsigned)j, v);
        g_w2[r*W2S + k2] = v;
        g_rowpT[k2*N + r] = np;
        dacc += unpackw(np);
      }
      for (int o = 32; o; o >>= 1) dacc += __shfl_xor(dacc, o);
      if (ln == 0) g_deg[r] = dacc;
    }
    GBAR();
    if (iter < NITER-1) {
      // first in-loop solve spans the A->S operator change: full cold solve.
      // later solves see small incremental changes: warm 1-round deg-12 solve
      // from orthonormal Y with theta-tightened filter window.
      if (iter == 0) EIG(ROUNDS_COLD, false, CHEB_M);
      else           EIG(ROUNDS_WARM, true, CHEB_WARM);
      if (t == 0) {
        double fn1 = 0.0;
        for (int i = 0; i < 8; i++) fn1 += sTheta[i];
        double fn2 = fn1 + sTheta[8];
        int done = sDoneV; float lam = sLamV;
        int c1 = (fn1 > 1e-10) ? 1 : 0;
        int c2 = ((!c1) && (fn2 < 1e-10)) ? 1 : 0;
        sF0 = !done;
        sF1 = (!done) && (!c2);
        if (!done) { if (c1) lam *= 2.f; else if (c2) lam *= 0.5f; sLamV = lam; }
        sDoneV = done || ((!c1) && (!c2));
      }
    } else {
      if (t == 0) { sF0 = !sDoneV; sF1 = 0; }
    }
    __syncthreads();
    if (sF0) {
      for (int k2 = t; k2 < 32*W1; k2 += NTHR) { int id = c*32*W1 + k2; g_s[id] = g_snew[id]; g_u[id] = g_unew[id]; }
      for (int k2 = t; k2 < 32*W2S; k2 += NTHR) { int id = c*32*W2S + k2; g_w2fin[id] = g_w2[id]; }
    }
    if (sF1) {
      if (t < 256) g_F[c*256 + t] = g_Fc[c*256 + t];
    }
    __syncthreads();
    if (t < 32) {                              // sn from (possibly updated) F
      int r = c*32 + t; float ss = 0.f;
      #pragma unroll
      for (int d = 0; d < 8; d++) { float v = g_F[r*8 + d]; ss += v*v; }
      g_sn[r] = ss;
    }
    GBAR();
  }

  // ================= outputs: S =================
  for (int s2 = 0; s2 < 2; s2++) {
    int r = c*32 + wv*2 + s2;
    if (ln < g_nnz1[r]) out[N + r*N + (int)g_idx1[r*W1 + ln]] = g_s[r*W1 + ln];
  }

  // ================= connected components (block 0) =================
  if (c == 0) {
    sLab[t] = t;
    __syncthreads();
    for (int it2 = 0; it2 < CCIT; it2++) {
      int nnz = g_nnz2[t];
      int m = sLab[t];
      for (int k2 = 0; k2 < nnz; k2++) {
        if (g_w2fin[t*W2S + k2] > 0.f) {
          int l2 = sLab[(int)g_jidx[t*W2S + k2]];
          m = m < l2 ? m : l2;
        }
      }
      sLab2[t] = m;
      __syncthreads();
      sLab[t] = sLab2[sLab2[t]];
      __syncthreads();
    }
    out[t] = (float)sLab[t];
  }
}

extern "C" void kernel_launch(void* const* d_in, const int* in_sizes, int n_in,
                              void* d_out, int out_size, void* d_ws, size_t ws_size,
                              hipStream_t stream) {
  const float* A = (const float*)d_in[0];
  float* out = (float*)d_out;

  void *pSd, *pFlags;
  hipGetSymbolAddress(&pSd,    HIP_SYMBOL(g_Sd));
  hipGetSymbolAddress(&pFlags, HIP_SYMBOL(g_flags));

  hipMemsetAsync(pSd, 0, sizeof(float)*(size_t)N*N, stream);
  hipMemsetAsync(pFlags, 0, sizeof(unsigned)*NB*32, stream);
  hipMemsetAsync(d_out, 0, sizeof(float)*(size_t)out_size, stream);

  mega<<<NB, NTHR, 0, stream>>>(A, out);
}

// Round 13
// 4016.463 us; speedup vs baseline: 1.8822x; 1.0040x over previous
//
#include <hip/hip_runtime.h>
#include <hip/hip_fp16.h>
#include <math.h>

#define N 1024
#define W1 64
#define W2S 96
#define Q 32
#define NB 32
#define NTHR 1024
#define CHEB_M 16
#define CHEB_WARM 12
#define ROUNDS_COLD0 2
#define ROUNDS_COLD 3
#define ROUNDS_WARM 1
#define NITER 6
#define NEWT 20
#define JSWEEPS 5
#define CCIT 8

#define WFENCE() asm volatile("" ::: "memory")

// ---------------- device state ----------------
__device__ unsigned g_flags[NB*32];
__device__ unsigned short g_idx1[N*W1];
__device__ float g_a0[N*W1], g_u[N*W1], g_unew[N*W1], g_s[N*W1], g_snew[N*W1];
__device__ int g_nnz1[N], g_nnz2[N], g_nz8[N];
__device__ unsigned g_rowpT[W2S*N];            // COLUMN-major packed: (idx<<16)|f16(w)
__device__ unsigned short g_jidx[N*W2S];       // row-major idx list
__device__ float g_w2[N*W2S], g_w2fin[N*W2S];
__device__ float g_deg[N], g_sn[N];
__device__ float g_Sd[N*N];
__device__ float g_X0[Q*N], g_X1[Q*N], g_W[Q*N];
__device__ double g_G[Q*Q], g_H[Q*Q];
__device__ float g_F[N*8];

__device__ __forceinline__ unsigned packrw(unsigned j, float w) {
  __half h = __float2half_rn(w);
  unsigned short bits; __builtin_memcpy(&bits, &h, 2);
  return (j << 16) | (unsigned)bits;
}
__device__ __forceinline__ float unpackw(unsigned v) {
  unsigned short bits = (unsigned short)(v & 0xFFFFu);
  __half h; __builtin_memcpy(&h, &bits, 2);
  return __half2float(h);
}

#define P1(acc, pv) { unsigned _p = (pv); acc += __half2float(__ushort_as_half((unsigned short)(_p & 0xFFFFu))) * xc[_p >> 16]; }

__global__ __launch_bounds__(NTHR) void mega(const float* __restrict__ A, float* __restrict__ out) {
  const int c = blockIdx.x;
  const int t = threadIdx.x;
  const int wv = t >> 6, ln = t & 63;

  __shared__ float xv[3][N];
  __shared__ float wl[N];
  __shared__ float degl[N];
  __shared__ double sM1[Q][Q+1];
  __shared__ double sM2[Q][Q+1];
  __shared__ double sM3[Q][Q+1];
  __shared__ float sFQ[Q][8];
  __shared__ float sFloc[32][8];
  __shared__ double sTheta[Q];
  __shared__ int   sPerm[Q];
  __shared__ float sCoef[CHEB_M*3];
  __shared__ float sRed[16];
  __shared__ int   sKw[16];
  __shared__ double sCs[16][2];
  __shared__ int   sPr[16], sQr[16];
  __shared__ int   sLab[N], sLab2[N];
  __shared__ float sB_, sA_, sLamV, sThQ;
  __shared__ int   sDoneV, sF0, sF1;

  float* xb = &xv[0][0];
  unsigned bcnt = 0;
  int cur = 1;   // after each publish (P = cur?X0:X1; cur^=1), (cur?X1:X0) = last published

  // one-hop symmetric barrier: every block's wave 0 polls all 32 flag lines
  auto GBAR = [&]() {
    __syncthreads();
    ++bcnt;
    if (t < 64) {
      if (ln == 0) {
        __builtin_amdgcn_fence(__ATOMIC_RELEASE, "agent");
        __hip_atomic_store(&g_flags[c*32], bcnt, __ATOMIC_RELAXED, __HIP_MEMORY_SCOPE_AGENT);
      }
      for (;;) {
        unsigned v = bcnt;
        if (ln < NB)
          v = __hip_atomic_load(&g_flags[ln*32], __ATOMIC_RELAXED, __HIP_MEMORY_SCOPE_AGENT);
        if (__all(v >= bcnt)) break;
        __builtin_amdgcn_s_sleep(2);
      }
      if (ln == 0) __builtin_amdgcn_fence(__ATOMIC_ACQUIRE, "agent");
    }
    __syncthreads();
  };

  // coalesced column-major ELL row-dot: thread t owns row t; wave-uniform bound
  auto SPROW = [&](const float* __restrict__ xc) -> float {
    float acc = 0.f, acc2 = 0.f;
    const int kmax = sKw[wv];
    const unsigned* __restrict__ rp = g_rowpT + t;
    for (int k = 0; k < kmax; k += 8) {
      const unsigned* __restrict__ p = rp + k*N;
      unsigned a0 = p[0*N], a1 = p[1*N], a2 = p[2*N], a3 = p[3*N];
      unsigned a4 = p[4*N], a5 = p[5*N], a6 = p[6*N], a7 = p[7*N];
      P1(acc, a0) P1(acc2, a1) P1(acc, a2) P1(acc2, a3)
      P1(acc, a4) P1(acc2, a5) P1(acc, a6) P1(acc2, a7)
    }
    return acc + acc2;
  };

  auto CHSTEP = [&](int cu_, int pv_, int nx, float al, float be, float ga) {
    const float* xc = xb + cu_*N;
    float acc = SPROW(xc);
    float xr = xc[t];
    float o = al*(degl[t]*xr - acc) + be*xr;
    if (ga != 0.f) o += ga * xb[pv_*N + t];
    xb[nx*N + t] = o;
    __syncthreads();
  };

  auto LMUL = [&](int cu_) {
    const float* xc = xb + cu_*N;
    float acc = SPROW(xc);
    wl[t] = degl[t]*xc[t] - acc;
    __syncthreads();
  };

  auto DEFL = [&](int bu) {
    if (c == 0) {
      xb[bu*N + t] = 0.03125f;
    } else {
      float s = xb[bu*N + t];
      for (int o = 32; o; o >>= 1) s += __shfl_xor(s, o);
      if (ln == 0) sRed[wv] = s;
      __syncthreads();
      float tot = 0.f;
      #pragma unroll
      for (int w = 0; w < 16; w++) tot += sRed[w];
      xb[bu*N + t] -= tot / (float)N;
    }
    __syncthreads();
  };

  auto GHROWS = [&](const float* Xp, int cu_) {
    const float* xc = xb + cu_*N;
    for (int k = wv; k < Q; k += 16) {
      const float* mx = Xp + k*N;
      const float* mw = g_W + k*N;
      double pg = 0.0, ph = 0.0;
      for (int s = 0; s < 16; s++) {
        int i = ln + s*64;
        double xv_ = (double)xc[i];
        pg += xv_ * (double)mx[i];
        ph += xv_ * (double)mw[i];
      }
      for (int o = 32; o; o >>= 1) { pg += __shfl_xor(pg, o); ph += __shfl_xor(ph, o); }
      if (ln == 0) { g_G[c*Q + k] = pg; g_H[c*Q + k] = ph; }
    }
  };

  // wave-0-local Cholesky + R^-1 (lockstep; WFENCE = compiler ordering only)
  auto CHOLINV = [&]() {
    for (int id = t; id < Q*Q; id += NTHR) sM1[id>>5][id&31] = g_G[id];
    __syncthreads();
    if (wv == 0) {
      const int j = ln & 31;
      const bool lo = ln < 32;
      double fl;
      { double md = 0.0;
        for (int i = 0; i < Q; i++) md = fmax(md, sM1[i][i]);
        fl = md*1e-13 + 1e-280; }
      for (int k = 0; k < Q; k++) {
        double dkk = sM1[k][k]; if (!(dkk > fl)) dkk = fl;
        double rkk = sqrt(dkk);
        if (lo && j > k) sM1[k][j] /= rkk;
        if (ln == 0) sM1[k][k] = rkk;
        WFENCE();
        if (lo) {
          for (int i = k+1; i < Q; i++)
            if (j >= i) sM1[i][j] -= sM1[k][i]*sM1[k][j];
        }
        WFENCE();
      }
      if (lo) {
        for (int i = 0; i < Q; i++) sM2[i][j] = 0.0;
        sM2[j][j] = 1.0/sM1[j][j];
        for (int i = j-1; i >= 0; i--) {
          double sa = 0.0;
          for (int k2 = i+1; k2 <= j; k2++) sa += sM1[i][k2]*sM2[k2][j];
          sM2[i][j] = -sa/sM1[i][i];
        }
      }
    }
    __syncthreads();
  };

  auto RRTRANS = [&]() {   // sM3 = R^-T * sM3 * R^-1
    int i = t >> 5, j = t & 31;
    double a = 0.0;
    for (int k = 0; k <= i; k++) a += sM2[k][i]*sM3[k][j];
    __syncthreads();
    sM1[i][j] = a;
    __syncthreads();
    double b = 0.0;
    for (int k = 0; k <= j; k++) b += sM1[i][k]*sM2[k][j];
    __syncthreads();
    sM3[i][j] = b;
    __syncthreads();
  };

  auto MULR = [&](const float* Xp, int tb) {   // xb[tb] = Xp * R^-1[:,c]  (orthonormal col)
    float acc = 0.f;
    #pragma unroll
    for (int k = 0; k < Q; k++) acc += Xp[k*N + t] * (float)sM2[k][c];
    xb[tb*N + t] = acc;
    __syncthreads();
  };

  auto POWA = [&]() {
    if (wv == 0) {
      int rl = ln & 31;
      double v = 1.0, w_ = 0.0, nrm = 1.0;
      for (int it = 0; it < 20; it++) {
        w_ = 0.0;
        for (int k2 = 0; k2 < Q; k2++) w_ += sM3[rl][k2]*__shfl(v, k2);
        nrm = 0.0;
        for (int k2 = 0; k2 < Q; k2++) { double wk = __shfl(w_, k2); nrm += wk*wk; }
        nrm = sqrt(nrm) + 1e-300;
        v = w_/nrm;
      }
      if (ln == 0) {
        float b = sB_;
        float a = (float)(nrm*1.1);
        if (a > 0.9f*b) a = 0.9f*b;
        if (a < 0.02f*b) a = 0.02f*b;
        sA_ = a;
      }
    }
    __syncthreads();
  };

  // wave-0-local Jacobi on sM3 (vectors accumulate in sM1)
  auto JACOBI = [&]() {
    for (int id = t; id < Q*Q; id += NTHR) sM1[id>>5][id&31] = ((id>>5) == (id&31)) ? 1.0 : 0.0;
    __syncthreads();
    if (wv == 0) {
      const int cj = ln & 31, half = ln >> 5;
      for (int sw = 0; sw < JSWEEPS; sw++) {
        for (int rr2 = 0; rr2 < 31; rr2++) {
          if (ln < 16) {
            int p, q;
            if (ln == 0) { p = 31; q = rr2 % 31; }
            else { p = (rr2 + ln) % 31; q = (rr2 + 31 - ln) % 31; }
            sPr[ln] = p; sQr[ln] = q;
            double app = sM3[p][p], aqq = sM3[q][q], apq = sM3[p][q];
            double cth, sth;
            if (fabs(apq) < 1e-280) { cth = 1.0; sth = 0.0; }
            else {
              double ta = (aqq - app)/(2.0*apq);
              double tt = (ta >= 0.0 ? 1.0 : -1.0)/(fabs(ta) + sqrt(1.0 + ta*ta));
              cth = 1.0/sqrt(1.0 + tt*tt); sth = tt*cth;
            }
            sCs[ln][0] = cth; sCs[ln][1] = sth;
          }
          WFENCE();
          #pragma unroll
          for (int s = 0; s < 8; s++) {
            int pi = 2*s + half;
            int p = sPr[pi], q = sQr[pi];
            double cth = sCs[pi][0], sth = sCs[pi][1];
            double hp = sM3[p][cj], hq = sM3[q][cj];
            sM3[p][cj] = cth*hp - sth*hq;
            sM3[q][cj] = sth*hp + cth*hq;
          }
          WFENCE();
          #pragma unroll
          for (int s = 0; s < 8; s++) {
            int pi = 2*s + half;
            int p = sPr[pi], q = sQr[pi];
            double cth = sCs[pi][0], sth = sCs[pi][1];
            double hp = sM3[cj][p], hq = sM3[cj][q];
            sM3[cj][p] = cth*hp - sth*hq;
            sM3[cj][q] = sth*hp + cth*hq;
            double vp = sM1[cj][p], vq = sM1[cj][q];
            sM1[cj][p] = cth*vp - sth*vq;
            sM1[cj][q] = sth*vp + cth*vq;
          }
          WFENCE();
        }
      }
      if (ln < Q) sTheta[ln] = sM3[ln][ln];
    }
    __syncthreads();
  };

  auto SORTP = [&]() {
    if (t == 0) {
      double th[Q]; int pm[Q];
      for (int i = 0; i < Q; i++) { th[i] = sTheta[i]; pm[i] = i; }
      for (int i = 1; i < Q; i++) {
        double x = th[i]; int px = pm[i]; int j = i - 1;
        while (j >= 0 && th[j] > x) { th[j+1] = th[j]; pm[j+1] = pm[j]; j--; }
        th[j+1] = x; pm[j+1] = px;
      }
      for (int i = 0; i < Q; i++) { sTheta[i] = th[i]; sPerm[i] = pm[i]; }
      sThQ = (float)th[Q-1];                 // largest tracked Ritz value
    }
    __syncthreads();
  };

  // EIG: leaves F for this block's 32 rows in sFloc (NOT committed), Y published
  // for next warm start, sTheta/sPerm valid. No trailing global barrier.
  auto EIG = [&](int nrounds, bool warm, int cm) {
    degl[t] = g_deg[t];
    __syncthreads();
    float mx = degl[t];
    for (int o = 32; o; o >>= 1) mx = fmaxf(mx, __shfl_xor(mx, o));
    if (ln == 0) sRed[wv] = mx;
    __syncthreads();
    if (t == 0) {
      float mm = 0.f;
      for (int w = 0; w < 16; w++) mm = fmaxf(mm, sRed[w]);
      float b = fmaxf(2.02f*mm, 1e-3f) + 1e-6f;
      float aa = 0.5f*b;
      if (warm) {
        float ta = 1.15f*sThQ;
        if (ta > 0.5f*b)  ta = 0.5f*b;
        if (ta < 0.02f*b) ta = 0.02f*b;
        aa = ta;
      }
      sB_ = b; sA_ = aa;
    }
    __syncthreads();
    {
      float v;
      if (c == 0) v = 0.03125f;
      else if (warm) v = (cur ? g_X1 : g_X0)[c*N + t];  // last published Y, own column
      else {
        unsigned h = (unsigned)t*1664525u + (unsigned)c*1013904223u + 12345u;
        h ^= h >> 16; h *= 2246822519u; h ^= h >> 13; h *= 3266489917u; h ^= h >> 16;
        v = ((float)(h & 0xFFFFFFu)/16777216.f) - 0.5f;
      }
      xb[t] = v;
    }
    __syncthreads();
    DEFL(0);
    int cu = 0;
    for (int round = 0; round < nrounds; round++) {
      if (t == 0) {
        double b = sB_, a = sA_;
        double e = 0.5*(b - a), cc = 0.5*(b + a);
        double s1 = e/(0.0 - cc);
        sCoef[0] = (float)(s1/e); sCoef[1] = (float)(-cc*(s1/e)); sCoef[2] = 0.f;
        double sp = s1;
        for (int k = 1; k < cm; k++) {
          double snn = 1.0/(2.0/s1 - sp);
          double a2 = 2.0*snn/e;
          sCoef[k*3] = (float)a2; sCoef[k*3+1] = (float)(-cc*a2); sCoef[k*3+2] = (float)(-sp*snn);
          sp = snn;
        }
      }
      __syncthreads();
      int pv_ = (cu+1)%3, nx = (cu+2)%3;
      for (int k = 0; k < cm; k++) {
        CHSTEP(cu, pv_, nx, sCoef[k*3], sCoef[k*3+1], sCoef[k*3+2]);
        int op = pv_; pv_ = cu; cu = nx; nx = op;
        if (k == 4 || k == 9 || k == cm-1) { DEFL(cu); DEFL(pv_); }
      }
      LMUL(cu);
      float* Xp = (cur ? g_X0 : g_X1);   // publish raw filtered basis
      cur ^= 1;
      Xp[c*N + t] = xb[cu*N + t];
      g_W[c*N + t] = wl[t];
      GBAR();                                      // X,W published
      GHROWS(Xp, cu);
      GBAR();                                      // G,Htilde complete
      for (int id = t; id < Q*Q; id += NTHR) sM3[id>>5][id&31] = g_H[id];
      CHOLINV();
      RRTRANS();
      if (round < nrounds-1) {
        POWA();
        MULR(Xp, 0); cu = 0;
      } else {
        JACOBI();
        SORTP();
        if (t < 256) {                             // FQ = R^-1 * V[:,perm(0..7)] (block-local f64)
          int k = t >> 3, cc2 = t & 7;
          int pc = sPerm[cc2];
          double a = 0.0;
          for (int m = 0; m < Q; m++) a += sM2[k][m]*sM1[m][pc];
          sFQ[k][cc2] = (float)a;
        }
        MULR(Xp, 0);                               // xb0 = own ORTHONORMAL Y col (also syncs sFQ)
        float* Yp = (cur ? g_X0 : g_X1);           // publish Y; only consumer is THIS block's
        cur ^= 1;                                  // next warm init (own column) -> no barrier
        Yp[c*N + t] = xb[t];
        if (t < 256) {                             // F for OWN 32 rows (block-local; same k-order
          int row = t >> 3, col = t & 7;           // as before -> bit-identical values)
          int gr = c*32 + row;
          float acc = 0.f;
          #pragma unroll
          for (int k = 0; k < Q; k++) acc += Xp[k*N + gr] * sFQ[k][col];
          sFloc[row][col] = acc;
        }
        __syncthreads();
      }
    }
  };

  // ================= BUILD =================
  for (int s2 = 0; s2 < 2; s2++) {
    int r = c*32 + wv*2 + s2;
    int cnt = 0;
    for (int c0 = 0; c0 < N; c0 += 64) {
      int j = c0 + ln;
      float v = A[r*N + j];
      bool keep = (j != r) && (v > 0.f);
      unsigned long long m = __ballot(keep);
      int pos = __popcll(m & ((1ull << ln) - 1ull));
      if (keep) {
        int w = cnt + pos;
        if (w < W1) { g_idx1[r*W1 + w] = (unsigned short)j; g_a0[r*W1 + w] = v; }
        g_Sd[j*N + r] = v;
      }
      cnt += __popcll(m);
    }
    cnt = cnt < W1 ? cnt : W1;
    if (ln == 0) g_nnz1[r] = cnt;
    g_u[r*W1 + ln] = 1.f;
    g_s[r*W1 + ln] = 0.f;
  }
  GBAR();
  for (int s2 = 0; s2 < 2; s2++) {
    int r = c*32 + wv*2 + s2;
    int cnt = 0; float dacc = 0.f;
    for (int c0 = 0; c0 < N; c0 += 64) {
      int j = c0 + ln;
      float vr = A[r*N + j];
      float vc = g_Sd[r*N + j];
      bool keep = (j != r) && (vr > 0.f || vc > 0.f);
      unsigned long long m = __ballot(keep);
      int pos = __popcll(m & ((1ull << ln) - 1ull));
      if (keep) {
        int w = cnt + pos;
        if (w < W2S) {
          float val = 0.5f*(vr + vc);
          unsigned pv = packrw((unsigned)j, val);
          g_rowpT[w*N + r] = pv;
          g_jidx[r*W2S + w] = (unsigned short)j;
          g_w2[r*W2S + w] = val;
          g_w2fin[r*W2S + w] = val;
          dacc += unpackw(pv);
        }
      }
      cnt += __popcll(m);
    }
    for (int o = 32; o; o >>= 1) dacc += __shfl_xor(dacc, o);
    cnt = cnt < W2S ? cnt : W2S;
    int nz8 = (cnt + 7) & ~7; if (nz8 < 8) nz8 = 8;
    if (ln == 0) { g_nnz2[r] = cnt; g_nz8[r] = nz8; g_deg[r] = dacc; }
    for (int w = cnt + ln; w < W2S; w += 64) {
      g_rowpT[w*N + r] = ((unsigned)r) << 16;    // zero-weight padding
      g_w2[r*W2S + w] = 0.f;
      g_w2fin[r*W2S + w] = 0.f;
    }
    for (int j = ln; j < N; j += 64) g_Sd[r*N + j] = 0.f;
  }
  GBAR();

  // per-wave static padded-nnz bound (thread t owns row t in the chain)
  {
    int m = g_nz8[t];
    for (int o = 32; o; o >>= 1) { int v = __shfl_xor(m, o); m = v > m ? v : m; }
    if (ln == 0) sKw[wv] = m;
    if (t == 0) { sLamV = 0.01f; sDoneV = 0; sThQ = 0.f; }
    __syncthreads();
  }

  // ================= initial (cold) eigensolve -> F, sn =================
  EIG(ROUNDS_COLD0, false, CHEB_M);
  if (t < 256) g_F[(c*32 + (t>>3))*8 + (t&7)] = sFloc[t>>3][t&7];
  __syncthreads();
  if (t < 32) {
    float ss = 0.f;
    #pragma unroll
    for (int d = 0; d < 8; d++) { float v = sFloc[t][d]; ss += v*v; }
    g_sn[c*32 + t] = ss;
  }
  GBAR();

  // ================= CLR iterations =================
  for (int iter = 0; iter < NITER; iter++) {
    {
      float lamreg = sLamV;
      for (int s2 = 0; s2 < 2; s2++) {
        int r = c*32 + wv*2 + s2;
        int nnz = g_nnz1[r];
        bool valid = ln < nnz;
        int e = r*W1 + ln;
        int cidx = valid ? (int)g_idx1[e] : 0;
        float a0v = valid ? g_a0[e] : 0.f;
        float uu = valid ? g_u[e] : 1.f;
        float fr[8];
        #pragma unroll
        for (int d = 0; d < 8; d++) fr[d] = g_F[r*8 + d];
        float dot = 0.f;
        #pragma unroll
        for (int d = 0; d < 8; d++) dot += fr[d]*g_F[cidx*8 + d];
        float dist = fmaxf(g_sn[r] + g_sn[cidx] - 2.f*dot, 0.f);
        float dd = uu*a0v - 0.5f*lamreg*dist;
        float tmin = valid ? (uu - dd) : 3.0e38f;
        for (int o = 32; o; o >>= 1) tmin = fminf(tmin, __shfl_xor(tmin, o));
        float lam = (tmin < 3.0e38f) ? tmin : 0.f;
        for (int it = 0; it < NEWT; it++) {
          float v1 = (lam + dd)/uu;
          bool pos = valid && (v1 > 0.f);
          float gg = pos ? (1.f/uu) : 0.f;
          float ff = pos ? v1 : 0.f;
          for (int o = 32; o; o >>= 1) { gg += __shfl_xor(gg, o); ff += __shfl_xor(ff, o); }
          float f = ff - 1.f;
          float step = f/(gg > 0.f ? gg : 1.f);
          lam = (fabsf(f) > 1e-8f) ? (lam - step) : lam;
        }
        float v1 = (lam + dd)/uu;
        float sv = fmaxf(v1, 0.f);
        if (valid) {
          g_snew[e] = sv;
          float df = sv - a0v;
          g_unew[e] = 1.f/(2.f*sqrtf(df*df + 2.2204e-16f));
          g_Sd[r*N + cidx] = sv;
        }
      }
    }
    GBAR();
    for (int s2 = 0; s2 < 2; s2++) {
      int r = c*32 + wv*2 + s2;
      int nnz = g_nnz2[r];
      float dacc = 0.f;
      for (int k2 = ln; k2 < nnz; k2 += 64) {
        int j = (int)g_jidx[r*W2S + k2];
        float v = 0.5f*(g_Sd[r*N + j] + g_Sd[j*N + r]);
        unsigned np = packrw((unsigned)j, v);
        g_w2[r*W2S + k2] = v;
        g_rowpT[k2*N + r] = np;
        dacc += unpackw(np);
      }
      for (int o = 32; o; o >>= 1) dacc += __shfl_xor(dacc, o);
      if (ln == 0) g_deg[r] = dacc;
    }
    GBAR();
    if (iter < NITER-1) {
      if (iter == 0) EIG(ROUNDS_COLD, false, CHEB_M);
      else           EIG(ROUNDS_WARM, true, CHEB_WARM);
      if (t == 0) {
        double fn1 = 0.0;
        for (int i = 0; i < 8; i++) fn1 += sTheta[i];
        double fn2 = fn1 + sTheta[8];
        int done = sDoneV; float lam = sLamV;
        int c1 = (fn1 > 1e-10) ? 1 : 0;
        int c2 = ((!c1) && (fn2 < 1e-10)) ? 1 : 0;
        sF0 = !done;
        sF1 = (!done) && (!c2);
        if (!done) { if (c1) lam *= 2.f; else if (c2) lam *= 0.5f; sLamV = lam; }
        sDoneV = done || ((!c1) && (!c2));
      }
    } else {
      if (t == 0) { sF0 = !sDoneV; sF1 = 0; }
    }
    __syncthreads();
    if (sF0) {
      for (int k2 = t; k2 < 32*W1; k2 += NTHR) { int id = c*32*W1 + k2; g_s[id] = g_snew[id]; g_u[id] = g_unew[id]; }
      for (int k2 = t; k2 < 32*W2S; k2 += NTHR) { int id = c*32*W2S + k2; g_w2fin[id] = g_w2[id]; }
    }
    if (sF1) {
      if (t < 256) g_F[(c*32 + (t>>3))*8 + (t&7)] = sFloc[t>>3][t&7];
    }
    __syncthreads();
    if (t < 32) {                              // sn from committed F (own rows)
      int r = c*32 + t; float ss = 0.f;
      #pragma unroll
      for (int d = 0; d < 8; d++) { float v = g_F[r*8 + d]; ss += v*v; }
      g_sn[r] = ss;
    }
    GBAR();                                    // F/S/u/w2fin all committed device-wide
  }

  // ================= outputs: S =================
  for (int s2 = 0; s2 < 2; s2++) {
    int r = c*32 + wv*2 + s2;
    if (ln < g_nnz1[r]) out[N + r*N + (int)g_idx1[r*W1 + ln]] = g_s[r*W1 + ln];
  }

  // ================= connected components (block 0) =================
  if (c == 0) {
    sLab[t] = t;
    __syncthreads();
    for (int it2 = 0; it2 < CCIT; it2++) {
      int nnz = g_nnz2[t];
      int m = sLab[t];
      for (int k2 = 0; k2 < nnz; k2++) {
        if (g_w2fin[t*W2S + k2] > 0.f) {
          int l2 = sLab[(int)g_jidx[t*W2S + k2]];
          m = m < l2 ? m : l2;
        }
      }
      sLab2[t] = m;
      __syncthreads();
      sLab[t] = sLab2[sLab2[t]];
      __syncthreads();
    }
    out[t] = (float)sLab[t];
  }
}

extern "C" void kernel_launch(void* const* d_in, const int* in_sizes, int n_in,
                              void* d_out, int out_size, void* d_ws, size_t ws_size,
                              hipStream_t stream) {
  const float* A = (const float*)d_in[0];
  float* out = (float*)d_out;

  void *pSd, *pFlags;
  hipGetSymbolAddress(&pSd,    HIP_SYMBOL(g_Sd));
  hipGetSymbolAddress(&pFlags, HIP_SYMBOL(g_flags));

  hipMemsetAsync(pSd, 0, sizeof(float)*(size_t)N*N, stream);
  hipMemsetAsync(pFlags, 0, sizeof(unsigned)*NB*32, stream);
  hipMemsetAsync(d_out, 0, sizeof(float)*(size_t)out_size, stream);

  mega<<<NB, NTHR, 0, stream>>>(A, out);
}

// Round 14
// 3434.621 us; speedup vs baseline: 2.2011x; 1.1694x over previous
//
#include <hip/hip_runtime.h>
#include <hip/hip_fp16.h>
#include <math.h>

#define N 1024
#define W1 64
#define W2S 96
#define Q 32
#define NB 32
#define NTHR 1024
#define CHEB_M 16
#define CHEB_WARM 12
#define ROUNDS_COLD0 2
#define ROUNDS_COLD 3
#define ROUNDS_WARM 1
#define NITER 6
#define NEWT 20
#define JSWEEPS 4
#define CCIT 8

#define WFENCE() asm volatile("" ::: "memory")

// ---------------- device state ----------------
__device__ unsigned g_flags[NB*32];
__device__ unsigned short g_idx1[N*W1];
__device__ float g_a0[N*W1], g_u[N*W1], g_unew[N*W1], g_s[N*W1], g_snew[N*W1];
__device__ int g_nnz1[N], g_nnz2[N], g_nz8[N];
__device__ unsigned g_rowpT[W2S*N];            // COLUMN-major packed: (idx<<16)|f16(w)
__device__ unsigned short g_jidx[N*W2S];       // row-major idx list
__device__ float g_w2[N*W2S], g_w2fin[N*W2S];
__device__ float g_deg[N], g_sn[N];
__device__ float g_Sd[N*N];
__device__ float g_X0[Q*N], g_X1[Q*N], g_W[Q*N];
__device__ double g_G[Q*Q], g_H[Q*Q];
__device__ float g_F[N*8];

__device__ __forceinline__ unsigned packrw(unsigned j, float w) {
  __half h = __float2half_rn(w);
  unsigned short bits; __builtin_memcpy(&bits, &h, 2);
  return (j << 16) | (unsigned)bits;
}
__device__ __forceinline__ float unpackw(unsigned v) {
  unsigned short bits = (unsigned short)(v & 0xFFFFu);
  __half h; __builtin_memcpy(&h, &bits, 2);
  return __half2float(h);
}

#define P1(acc, pv) { unsigned _p = (pv); acc += __half2float(__ushort_as_half((unsigned short)(_p & 0xFFFFu))) * xc[_p >> 16]; }

__global__ __launch_bounds__(NTHR) void mega(const float* __restrict__ A, float* __restrict__ out) {
  const int c = blockIdx.x;
  const int t = threadIdx.x;
  const int wv = t >> 6, ln = t & 63;

  __shared__ float xv[3][N];
  __shared__ float wl[N];
  __shared__ float degl[N];
  __shared__ double sM1[Q][Q+1];
  __shared__ double sM2[Q][Q+1];
  __shared__ double sM3[Q][Q+1];
  __shared__ float sJ[Q][Q+1];     // f32 RR matrix (Jacobi workspace / POWA input)
  __shared__ float sVv[Q][Q+1];    // f32 eigenvector accumulator
  __shared__ float sFQ[Q][8];
  __shared__ float sFloc[32][8];
  __shared__ double sTheta[Q];
  __shared__ int   sPerm[Q];
  __shared__ float sCoef[CHEB_M*3];
  __shared__ float sRed[16];
  __shared__ int   sKw[16];
  __shared__ float sCsF[16][2];
  __shared__ int   sPr[16], sQr[16];
  __shared__ int   sLab[N], sLab2[N];
  __shared__ float sB_, sA_, sLamV, sThQ;
  __shared__ int   sDoneV, sF0, sF1;

  float* xb = &xv[0][0];
  unsigned bcnt = 0;
  int cur = 1;   // after each publish (P = cur?X0:X1; cur^=1), (cur?X1:X0) = last published

  // one-hop symmetric barrier: every block's wave 0 polls all 32 flag lines
  auto GBAR = [&]() {
    __syncthreads();
    ++bcnt;
    if (t < 64) {
      if (ln == 0) {
        __builtin_amdgcn_fence(__ATOMIC_RELEASE, "agent");
        __hip_atomic_store(&g_flags[c*32], bcnt, __ATOMIC_RELAXED, __HIP_MEMORY_SCOPE_AGENT);
      }
      for (;;) {
        unsigned v = bcnt;
        if (ln < NB)
          v = __hip_atomic_load(&g_flags[ln*32], __ATOMIC_RELAXED, __HIP_MEMORY_SCOPE_AGENT);
        if (__all(v >= bcnt)) break;
        __builtin_amdgcn_s_sleep(2);
      }
      if (ln == 0) __builtin_amdgcn_fence(__ATOMIC_ACQUIRE, "agent");
    }
    __syncthreads();
  };

  // coalesced column-major ELL row-dot: thread t owns row t; wave-uniform bound
  auto SPROW = [&](const float* __restrict__ xc) -> float {
    float acc = 0.f, acc2 = 0.f;
    const int kmax = sKw[wv];
    const unsigned* __restrict__ rp = g_rowpT + t;
    for (int k = 0; k < kmax; k += 8) {
      const unsigned* __restrict__ p = rp + k*N;
      unsigned a0 = p[0*N], a1 = p[1*N], a2 = p[2*N], a3 = p[3*N];
      unsigned a4 = p[4*N], a5 = p[5*N], a6 = p[6*N], a7 = p[7*N];
      P1(acc, a0) P1(acc2, a1) P1(acc, a2) P1(acc2, a3)
      P1(acc, a4) P1(acc2, a5) P1(acc, a6) P1(acc2, a7)
    }
    return acc + acc2;
  };

  auto CHSTEP = [&](int cu_, int pv_, int nx, float al, float be, float ga) {
    const float* xc = xb + cu_*N;
    float acc = SPROW(xc);
    float xr = xc[t];
    float o = al*(degl[t]*xr - acc) + be*xr;
    if (ga != 0.f) o += ga * xb[pv_*N + t];
    xb[nx*N + t] = o;
    __syncthreads();
  };

  auto LMUL = [&](int cu_) {
    const float* xc = xb + cu_*N;
    float acc = SPROW(xc);
    wl[t] = degl[t]*xc[t] - acc;
    __syncthreads();
  };

  auto DEFL = [&](int bu) {
    if (c == 0) {
      xb[bu*N + t] = 0.03125f;
    } else {
      float s = xb[bu*N + t];
      for (int o = 32; o; o >>= 1) s += __shfl_xor(s, o);
      if (ln == 0) sRed[wv] = s;
      __syncthreads();
      float tot = 0.f;
      #pragma unroll
      for (int w = 0; w < 16; w++) tot += sRed[w];
      xb[bu*N + t] -= tot / (float)N;
    }
    __syncthreads();
  };

  auto GHROWS = [&](const float* Xp, int cu_) {
    const float* xc = xb + cu_*N;
    for (int k = wv; k < Q; k += 16) {
      const float* mx = Xp + k*N;
      const float* mw = g_W + k*N;
      double pg = 0.0, ph = 0.0;
      for (int s = 0; s < 16; s++) {
        int i = ln + s*64;
        double xv_ = (double)xc[i];
        pg += xv_ * (double)mx[i];
        ph += xv_ * (double)mw[i];
      }
      for (int o = 32; o; o >>= 1) { pg += __shfl_xor(pg, o); ph += __shfl_xor(ph, o); }
      if (ln == 0) { g_G[c*Q + k] = pg; g_H[c*Q + k] = ph; }
    }
  };

  // wave-0-local Cholesky + R^-1 (lockstep; WFENCE = compiler ordering only)
  auto CHOLINV = [&]() {
    for (int id = t; id < Q*Q; id += NTHR) sM1[id>>5][id&31] = g_G[id];
    __syncthreads();
    if (wv == 0) {
      const int j = ln & 31;
      const bool lo = ln < 32;
      double fl;
      { double md = 0.0;
        for (int i = 0; i < Q; i++) md = fmax(md, sM1[i][i]);
        fl = md*1e-13 + 1e-280; }
      for (int k = 0; k < Q; k++) {
        double dkk = sM1[k][k]; if (!(dkk > fl)) dkk = fl;
        double rkk = sqrt(dkk);
        if (lo && j > k) sM1[k][j] /= rkk;
        if (ln == 0) sM1[k][k] = rkk;
        WFENCE();
        if (lo) {
          for (int i = k+1; i < Q; i++)
            if (j >= i) sM1[i][j] -= sM1[k][i]*sM1[k][j];
        }
        WFENCE();
      }
      if (lo) {
        for (int i = 0; i < Q; i++) sM2[i][j] = 0.0;
        sM2[j][j] = 1.0/sM1[j][j];
        for (int i = j-1; i >= 0; i--) {
          double sa = 0.0;
          for (int k2 = i+1; k2 <= j; k2++) sa += sM1[i][k2]*sM2[k2][j];
          sM2[i][j] = -sa/sM1[i][i];
        }
      }
    }
    __syncthreads();
  };

  auto RRTRANS = [&]() {   // sM3 = R^-T * sM3 * R^-1 ; also cast result into sJ (f32)
    int i = t >> 5, j = t & 31;
    double a = 0.0;
    for (int k = 0; k <= i; k++) a += sM2[k][i]*sM3[k][j];
    __syncthreads();
    sM1[i][j] = a;
    __syncthreads();
    double b = 0.0;
    for (int k = 0; k <= j; k++) b += sM1[i][k]*sM2[k][j];
    __syncthreads();
    sM3[i][j] = b;
    sJ[i][j] = (float)b;
    __syncthreads();
  };

  auto MULR = [&](const float* Xp, int tb) {   // xb[tb] = Xp * R^-1[:,c]  (orthonormal col)
    float acc = 0.f;
    #pragma unroll
    for (int k = 0; k < Q; k++) acc += Xp[k*N + t] * (float)sM2[k][c];
    xb[tb*N + t] = acc;
    __syncthreads();
  };

  // f32 power iteration on sJ
  auto POWA = [&]() {
    if (wv == 0) {
      int rl = ln & 31;
      float v = 1.f, w_ = 0.f, nrm = 1.f;
      for (int it = 0; it < 20; it++) {
        w_ = 0.f;
        for (int k2 = 0; k2 < Q; k2++) w_ += sJ[rl][k2]*__shfl(v, k2);
        nrm = 0.f;
        for (int k2 = 0; k2 < Q; k2++) { float wk = __shfl(w_, k2); nrm += wk*wk; }
        nrm = sqrtf(nrm) + 1e-30f;
        v = w_/nrm;
      }
      if (ln == 0) {
        float b = sB_;
        float a = nrm*1.1f;
        if (a > 0.9f*b) a = 0.9f*b;
        if (a < 0.02f*b) a = 0.02f*b;
        sA_ = a;
      }
    }
    __syncthreads();
  };

  // wave-0-local f32 Jacobi on sJ (vectors accumulate in sVv)
  auto JACOBI = [&]() {
    for (int id = t; id < Q*Q; id += NTHR) sVv[id>>5][id&31] = ((id>>5) == (id&31)) ? 1.f : 0.f;
    __syncthreads();
    if (wv == 0) {
      const int cj = ln & 31, half = ln >> 5;
      for (int sw = 0; sw < JSWEEPS; sw++) {
        for (int rr2 = 0; rr2 < 31; rr2++) {
          if (ln < 16) {
            int p, q;
            if (ln == 0) { p = 31; q = rr2 % 31; }
            else { p = (rr2 + ln) % 31; q = (rr2 + 31 - ln) % 31; }
            sPr[ln] = p; sQr[ln] = q;
            float app = sJ[p][p], aqq = sJ[q][q], apq = sJ[p][q];
            float cth, sth;
            if (fabsf(apq) < 1e-30f) { cth = 1.f; sth = 0.f; }
            else {
              float ta = (aqq - app)/(2.f*apq);
              float tt = (ta >= 0.f ? 1.f : -1.f)/(fabsf(ta) + sqrtf(1.f + ta*ta));
              cth = rsqrtf(1.f + tt*tt); sth = tt*cth;
            }
            sCsF[ln][0] = cth; sCsF[ln][1] = sth;
          }
          WFENCE();
          #pragma unroll
          for (int s = 0; s < 8; s++) {
            int pi = 2*s + half;
            int p = sPr[pi], q = sQr[pi];
            float cth = sCsF[pi][0], sth = sCsF[pi][1];
            float hp = sJ[p][cj], hq = sJ[q][cj];
            sJ[p][cj] = cth*hp - sth*hq;
            sJ[q][cj] = sth*hp + cth*hq;
          }
          WFENCE();
          #pragma unroll
          for (int s = 0; s < 8; s++) {
            int pi = 2*s + half;
            int p = sPr[pi], q = sQr[pi];
            float cth = sCsF[pi][0], sth = sCsF[pi][1];
            float hp = sJ[cj][p], hq = sJ[cj][q];
            sJ[cj][p] = cth*hp - sth*hq;
            sJ[cj][q] = sth*hp + cth*hq;
            float vp = sVv[cj][p], vq = sVv[cj][q];
            sVv[cj][p] = cth*vp - sth*vq;
            sVv[cj][q] = sth*vp + cth*vq;
          }
          WFENCE();
        }
      }
      if (ln < Q) sTheta[ln] = (double)sJ[ln][ln];
    }
    __syncthreads();
  };

  auto SORTP = [&]() {
    if (t == 0) {
      double th[Q]; int pm[Q];
      for (int i = 0; i < Q; i++) { th[i] = sTheta[i]; pm[i] = i; }
      for (int i = 1; i < Q; i++) {
        double x = th[i]; int px = pm[i]; int j = i - 1;
        while (j >= 0 && th[j] > x) { th[j+1] = th[j]; pm[j+1] = pm[j]; j--; }
        th[j+1] = x; pm[j+1] = px;
      }
      for (int i = 0; i < Q; i++) { sTheta[i] = th[i]; sPerm[i] = pm[i]; }
      sThQ = (float)th[Q-1];                 // largest tracked Ritz value
    }
    __syncthreads();
  };

  // EIG: leaves F for this block's 32 rows in sFloc (NOT committed), Y published
  // for next warm start, sTheta/sPerm valid. No trailing global barrier.
  auto EIG = [&](int nrounds, bool warm, int cm) {
    degl[t] = g_deg[t];
    __syncthreads();
    float mx = degl[t];
    for (int o = 32; o; o >>= 1) mx = fmaxf(mx, __shfl_xor(mx, o));
    if (ln == 0) sRed[wv] = mx;
    __syncthreads();
    if (t == 0) {
      float mm = 0.f;
      for (int w = 0; w < 16; w++) mm = fmaxf(mm, sRed[w]);
      float b = fmaxf(2.02f*mm, 1e-3f) + 1e-6f;
      float aa = 0.5f*b;
      if (warm) {
        float ta = 1.15f*sThQ;
        if (ta > 0.5f*b)  ta = 0.5f*b;
        if (ta < 0.02f*b) ta = 0.02f*b;
        aa = ta;
      }
      sB_ = b; sA_ = aa;
    }
    __syncthreads();
    {
      float v;
      if (c == 0) v = 0.03125f;
      else if (warm) v = (cur ? g_X1 : g_X0)[c*N + t];  // last published Y, own column
      else {
        unsigned h = (unsigned)t*1664525u + (unsigned)c*1013904223u + 12345u;
        h ^= h >> 16; h *= 2246822519u; h ^= h >> 13; h *= 3266489917u; h ^= h >> 16;
        v = ((float)(h & 0xFFFFFFu)/16777216.f) - 0.5f;
      }
      xb[t] = v;
    }
    __syncthreads();
    DEFL(0);
    int cu = 0;
    for (int round = 0; round < nrounds; round++) {
      if (t == 0) {
        double b = sB_, a = sA_;
        double e = 0.5*(b - a), cc = 0.5*(b + a);
        double s1 = e/(0.0 - cc);
        sCoef[0] = (float)(s1/e); sCoef[1] = (float)(-cc*(s1/e)); sCoef[2] = 0.f;
        double sp = s1;
        for (int k = 1; k < cm; k++) {
          double snn = 1.0/(2.0/s1 - sp);
          double a2 = 2.0*snn/e;
          sCoef[k*3] = (float)a2; sCoef[k*3+1] = (float)(-cc*a2); sCoef[k*3+2] = (float)(-sp*snn);
          sp = snn;
        }
      }
      __syncthreads();
      int pv_ = (cu+1)%3, nx = (cu+2)%3;
      for (int k = 0; k < cm; k++) {
        CHSTEP(cu, pv_, nx, sCoef[k*3], sCoef[k*3+1], sCoef[k*3+2]);
        int op = pv_; pv_ = cu; cu = nx; nx = op;
        if (k == 4 || k == 9 || k == cm-1) { DEFL(cu); DEFL(pv_); }
      }
      LMUL(cu);
      float* Xp = (cur ? g_X0 : g_X1);   // publish raw filtered basis
      cur ^= 1;
      Xp[c*N + t] = xb[cu*N + t];
      g_W[c*N + t] = wl[t];
      GBAR();                                      // X,W published
      GHROWS(Xp, cu);
      GBAR();                                      // G,Htilde complete
      for (int id = t; id < Q*Q; id += NTHR) sM3[id>>5][id&31] = g_H[id];
      CHOLINV();
      RRTRANS();                                   // also fills sJ (f32 copy)
      if (round < nrounds-1) {
        POWA();
        MULR(Xp, 0); cu = 0;
      } else {
        JACOBI();
        SORTP();
        if (t < 256) {                             // FQ = R^-1 * V[:,perm(0..7)] (block-local)
          int k = t >> 3, cc2 = t & 7;
          int pc = sPerm[cc2];
          double a = 0.0;
          for (int m = 0; m < Q; m++) a += sM2[k][m]*(double)sVv[m][pc];
          sFQ[k][cc2] = (float)a;
        }
        MULR(Xp, 0);                               // xb0 = own ORTHONORMAL Y col (also syncs sFQ)
        float* Yp = (cur ? g_X0 : g_X1);           // publish Y; only consumer is THIS block's
        cur ^= 1;                                  // next warm init (own column) -> no barrier
        Yp[c*N + t] = xb[t];
        if (t < 256) {                             // F for OWN 32 rows (block-local)
          int row = t >> 3, col = t & 7;
          int gr = c*32 + row;
          float acc = 0.f;
          #pragma unroll
          for (int k = 0; k < Q; k++) acc += Xp[k*N + gr] * sFQ[k][col];
          sFloc[row][col] = acc;
        }
        __syncthreads();
      }
    }
  };

  // ================= BUILD =================
  for (int s2 = 0; s2 < 2; s2++) {
    int r = c*32 + wv*2 + s2;
    int cnt = 0;
    for (int c0 = 0; c0 < N; c0 += 64) {
      int j = c0 + ln;
      float v = A[r*N + j];
      bool keep = (j != r) && (v > 0.f);
      unsigned long long m = __ballot(keep);
      int pos = __popcll(m & ((1ull << ln) - 1ull));
      if (keep) {
        int w = cnt + pos;
        if (w < W1) { g_idx1[r*W1 + w] = (unsigned short)j; g_a0[r*W1 + w] = v; }
        g_Sd[j*N + r] = v;
      }
      cnt += __popcll(m);
    }
    cnt = cnt < W1 ? cnt : W1;
    if (ln == 0) g_nnz1[r] = cnt;
    g_u[r*W1 + ln] = 1.f;
    g_s[r*W1 + ln] = 0.f;
  }
  GBAR();
  for (int s2 = 0; s2 < 2; s2++) {
    int r = c*32 + wv*2 + s2;
    int cnt = 0; float dacc = 0.f;
    for (int c0 = 0; c0 < N; c0 += 64) {
      int j = c0 + ln;
      float vr = A[r*N + j];
      float vc = g_Sd[r*N + j];
      bool keep = (j != r) && (vr > 0.f || vc > 0.f);
      unsigned long long m = __ballot(keep);
      int pos = __popcll(m & ((1ull << ln) - 1ull));
      if (keep) {
        int w = cnt + pos;
        if (w < W2S) {
          float val = 0.5f*(vr + vc);
          unsigned pv = packrw((unsigned)j, val);
          g_rowpT[w*N + r] = pv;
          g_jidx[r*W2S + w] = (unsigned short)j;
          g_w2[r*W2S + w] = val;
          g_w2fin[r*W2S + w] = val;
          dacc += unpackw(pv);
        }
      }
      cnt += __popcll(m);
    }
    for (int o = 32; o; o >>= 1) dacc += __shfl_xor(dacc, o);
    cnt = cnt < W2S ? cnt : W2S;
    int nz8 = (cnt + 7) & ~7; if (nz8 < 8) nz8 = 8;
    if (ln == 0) { g_nnz2[r] = cnt; g_nz8[r] = nz8; g_deg[r] = dacc; }
    for (int w = cnt + ln; w < W2S; w += 64) {
      g_rowpT[w*N + r] = ((unsigned)r) << 16;    // zero-weight padding
      g_w2[r*W2S + w] = 0.f;
      g_w2fin[r*W2S + w] = 0.f;
    }
    for (int j = ln; j < N; j += 64) g_Sd[r*N + j] = 0.f;
  }
  GBAR();

  // per-wave static padded-nnz bound (thread t owns row t in the chain)
  {
    int m = g_nz8[t];
    for (int o = 32; o; o >>= 1) { int v = __shfl_xor(m, o); m = v > m ? v : m; }
    if (ln == 0) sKw[wv] = m;
    if (t == 0) { sLamV = 0.01f; sDoneV = 0; sThQ = 0.f; }
    __syncthreads();
  }

  // ================= initial (cold) eigensolve -> F, sn =================
  EIG(ROUNDS_COLD0, false, CHEB_M);
  if (t < 256) g_F[(c*32 + (t>>3))*8 + (t&7)] = sFloc[t>>3][t&7];
  __syncthreads();
  if (t < 32) {
    float ss = 0.f;
    #pragma unroll
    for (int d = 0; d < 8; d++) { float v = sFloc[t][d]; ss += v*v; }
    g_sn[c*32 + t] = ss;
  }
  GBAR();

  // ================= CLR iterations =================
  for (int iter = 0; iter < NITER; iter++) {
    {
      float lamreg = sLamV;
      for (int s2 = 0; s2 < 2; s2++) {
        int r = c*32 + wv*2 + s2;
        int nnz = g_nnz1[r];
        bool valid = ln < nnz;
        int e = r*W1 + ln;
        int cidx = valid ? (int)g_idx1[e] : 0;
        float a0v = valid ? g_a0[e] : 0.f;
        float uu = valid ? g_u[e] : 1.f;
        float fr[8];
        #pragma unroll
        for (int d = 0; d < 8; d++) fr[d] = g_F[r*8 + d];
        float dot = 0.f;
        #pragma unroll
        for (int d = 0; d < 8; d++) dot += fr[d]*g_F[cidx*8 + d];
        float dist = fmaxf(g_sn[r] + g_sn[cidx] - 2.f*dot, 0.f);
        float dd = uu*a0v - 0.5f*lamreg*dist;
        float tmin = valid ? (uu - dd) : 3.0e38f;
        for (int o = 32; o; o >>= 1) tmin = fminf(tmin, __shfl_xor(tmin, o));
        float lam = (tmin < 3.0e38f) ? tmin : 0.f;
        for (int it = 0; it < NEWT; it++) {
          float v1 = (lam + dd)/uu;
          bool pos = valid && (v1 > 0.f);
          float gg = pos ? (1.f/uu) : 0.f;
          float ff = pos ? v1 : 0.f;
          for (int o = 32; o; o >>= 1) { gg += __shfl_xor(gg, o); ff += __shfl_xor(ff, o); }
          float f = ff - 1.f;
          float step = f/(gg > 0.f ? gg : 1.f);
          lam = (fabsf(f) > 1e-8f) ? (lam - step) : lam;
        }
        float v1 = (lam + dd)/uu;
        float sv = fmaxf(v1, 0.f);
        if (valid) {
          g_snew[e] = sv;
          float df = sv - a0v;
          g_unew[e] = 1.f/(2.f*sqrtf(df*df + 2.2204e-16f));
          g_Sd[r*N + cidx] = sv;
        }
      }
    }
    GBAR();
    for (int s2 = 0; s2 < 2; s2++) {
      int r = c*32 + wv*2 + s2;
      int nnz = g_nnz2[r];
      float dacc = 0.f;
      for (int k2 = ln; k2 < nnz; k2 += 64) {
        int j = (int)g_jidx[r*W2S + k2];
        float v = 0.5f*(g_Sd[r*N + j] + g_Sd[j*N + r]);
        unsigned np = packrw((unsigned)j, v);
        g_w2[r*W2S + k2] = v;
        g_rowpT[k2*N + r] = np;
        dacc += unpackw(np);
      }
      for (int o = 32; o; o >>= 1) dacc += __shfl_xor(dacc, o);
      if (ln == 0) g_deg[r] = dacc;
    }
    GBAR();
    if (iter < NITER-1) {
      if (iter == 0) EIG(ROUNDS_COLD, false, CHEB_M);
      else           EIG(ROUNDS_WARM, true, CHEB_WARM);
      if (t == 0) {
        double fn1 = 0.0;
        for (int i = 0; i < 8; i++) fn1 += sTheta[i];
        double fn2 = fn1 + sTheta[8];
        int done = sDoneV; float lam = sLamV;
        int c1 = (fn1 > 1e-10) ? 1 : 0;
        int c2 = ((!c1) && (fn2 < 1e-10)) ? 1 : 0;
        sF0 = !done;
        sF1 = (!done) && (!c2);
        if (!done) { if (c1) lam *= 2.f; else if (c2) lam *= 0.5f; sLamV = lam; }
        sDoneV = done || ((!c1) && (!c2));
      }
    } else {
      if (t == 0) { sF0 = !sDoneV; sF1 = 0; }
    }
    __syncthreads();
    if (sF0) {
      for (int k2 = t; k2 < 32*W1; k2 += NTHR) { int id = c*32*W1 + k2; g_s[id] = g_snew[id]; g_u[id] = g_unew[id]; }
      for (int k2 = t; k2 < 32*W2S; k2 += NTHR) { int id = c*32*W2S + k2; g_w2fin[id] = g_w2[id]; }
    }
    if (sF1) {
      if (t < 256) g_F[(c*32 + (t>>3))*8 + (t&7)] = sFloc[t>>3][t&7];
    }
    __syncthreads();
    if (t < 32) {                              // sn from committed F (own rows)
      int r = c*32 + t; float ss = 0.f;
      #pragma unroll
      for (int d = 0; d < 8; d++) { float v = g_F[r*8 + d]; ss += v*v; }
      g_sn[r] = ss;
    }
    GBAR();                                    // F/S/u/w2fin all committed device-wide
  }

  // ================= outputs: S =================
  for (int s2 = 0; s2 < 2; s2++) {
    int r = c*32 + wv*2 + s2;
    if (ln < g_nnz1[r]) out[N + r*N + (int)g_idx1[r*W1 + ln]] = g_s[r*W1 + ln];
  }

  // ================= connected components (block 0) =================
  if (c == 0) {
    sLab[t] = t;
    __syncthreads();
    for (int it2 = 0; it2 < CCIT; it2++) {
      int nnz = g_nnz2[t];
      int m = sLab[t];
      for (int k2 = 0; k2 < nnz; k2++) {
        if (g_w2fin[t*W2S + k2] > 0.f) {
          int l2 = sLab[(int)g_jidx[t*W2S + k2]];
          m = m < l2 ? m : l2;
        }
      }
      sLab2[t] = m;
      __syncthreads();
      sLab[t] = sLab2[sLab2[t]];
      __syncthreads();
    }
    out[t] = (float)sLab[t];
  }
}

extern "C" void kernel_launch(void* const* d_in, const int* in_sizes, int n_in,
                              void* d_out, int out_size, void* d_ws, size_t ws_size,
                              hipStream_t stream) {
  const float* A = (const float*)d_in[0];
  float* out = (float*)d_out;

  void *pSd, *pFlags;
  hipGetSymbolAddress(&pSd,    HIP_SYMBOL(g_Sd));
  hipGetSymbolAddress(&pFlags, HIP_SYMBOL(g_flags));

  hipMemsetAsync(pSd, 0, sizeof(float)*(size_t)N*N, stream);
  hipMemsetAsync(pFlags, 0, sizeof(unsigned)*NB*32, stream);
  hipMemsetAsync(d_out, 0, sizeof(float)*(size_t)out_size, stream);

  mega<<<NB, NTHR, 0, stream>>>(A, out);
}